// Round 8
// baseline (292.334 us; speedup 1.0000x reference)
//
#include <hip/hip_runtime.h>
#include <math.h>

#define N_ROWS 16384
#define K_CODES 4096
#define D_DIM 512
#define NCHUNK 8
#define KCHUNK (K_CODES / NCHUNK)
#define MARGIN 2.5e-3f
#define CCAP 32   // per-row per-chunk candidate cap (expected ~1-4 used)

typedef unsigned int uint32;
typedef unsigned short u16t;
typedef __attribute__((ext_vector_type(8))) short short8;
typedef __attribute__((ext_vector_type(4))) float f32x4;

__device__ __forceinline__ float fmul_(float a, float b) { return __fmul_rn(a, b); }
__device__ __forceinline__ float fadd_(float a, float b) { return __fadd_rn(a, b); }

// ---------------------------------------------------------------- cvt bf16
__device__ __forceinline__ u16t f2bf(float x) {
    uint32 u = __float_as_uint(x);
    return (u16t)((u + 0x7fffu + ((u >> 16) & 1u)) >> 16);   // RNE
}
// order-preserving float<->uint key for LDS atomicMin on floats (incl. negatives)
__device__ __forceinline__ uint32 fkey(float f) {
    uint32 u = __float_as_uint(f);
    return (u & 0x80000000u) ? ~u : (u | 0x80000000u);
}
__device__ __forceinline__ float fdec(uint32 k) {
    uint32 u = (k & 0x80000000u) ? (k ^ 0x80000000u) : ~k;
    return __uint_as_float(u);
}
// min across each contiguous 16-lane group, pure-VALU DPP (no ds_swizzle).
__device__ __forceinline__ float dpp_min16(float x) {
    int y;
    y = __builtin_amdgcn_update_dpp(0, __float_as_int(x), 0xB1, 0xf, 0xf, true);
    x = fminf(x, __int_as_float(y));
    y = __builtin_amdgcn_update_dpp(0, __float_as_int(x), 0x4E, 0xf, 0xf, true);
    x = fminf(x, __int_as_float(y));
    y = __builtin_amdgcn_update_dpp(0, __float_as_int(x), 0x141, 0xf, 0xf, true);
    x = fminf(x, __int_as_float(y));
    y = __builtin_amdgcn_update_dpp(0, __float_as_int(x), 0x140, 0xf, 0xf, true);
    x = fminf(x, __int_as_float(y));
    return x;
}

// ---------------------------------------------------------------- prep
// FUSED cvt_bf16 + rownorm (verified R7): reads each input once, row-norm
// arithmetic byte-identical to the verified rownorm_np_kernel.
__global__ void prep_kernel(const float* __restrict__ z,
                            const float* __restrict__ cb,
                            u16t* __restrict__ z_bf, u16t* __restrict__ cb_bf,
                            float* __restrict__ zz, float* __restrict__ cnorm) {
    int gid = blockIdx.x * blockDim.x + threadIdx.x;
    int row = gid >> 2;
    int blk = gid & 3;
    const float* src;
    u16t* dst;
    float* outn;
    if (row < N_ROWS) {
        src = z + (size_t)row * D_DIM;
        dst = z_bf + (size_t)row * D_DIM;
        outn = zz + row;
    } else {
        int r = row - N_ROWS;
        if (r >= K_CODES) return;
        src = cb + (size_t)r * D_DIM;
        dst = cb_bf + (size_t)r * D_DIM;
        outn = cnorm + r;
    }
    const float4* p = (const float4*)(src + blk * 128);
    u16t* d = dst + blk * 128;
    float4 v0 = p[0], v1 = p[1];
    {
        short8 o;
        o[0] = (short)f2bf(v0.x); o[1] = (short)f2bf(v0.y);
        o[2] = (short)f2bf(v0.z); o[3] = (short)f2bf(v0.w);
        o[4] = (short)f2bf(v1.x); o[5] = (short)f2bf(v1.y);
        o[6] = (short)f2bf(v1.z); o[7] = (short)f2bf(v1.w);
        *(short8*)d = o;
    }
    float r0 = fmul_(v0.x, v0.x), r1 = fmul_(v0.y, v0.y);
    float r2 = fmul_(v0.z, v0.z), r3 = fmul_(v0.w, v0.w);
    float r4 = fmul_(v1.x, v1.x), r5 = fmul_(v1.y, v1.y);
    float r6 = fmul_(v1.z, v1.z), r7 = fmul_(v1.w, v1.w);
#pragma unroll
    for (int i = 1; i < 16; i++) {
        float4 w0 = p[2 * i], w1 = p[2 * i + 1];
        {
            short8 o;
            o[0] = (short)f2bf(w0.x); o[1] = (short)f2bf(w0.y);
            o[2] = (short)f2bf(w0.z); o[3] = (short)f2bf(w0.w);
            o[4] = (short)f2bf(w1.x); o[5] = (short)f2bf(w1.y);
            o[6] = (short)f2bf(w1.z); o[7] = (short)f2bf(w1.w);
            *(short8*)(d + i * 8) = o;
        }
        r0 = fadd_(r0, fmul_(w0.x, w0.x));
        r1 = fadd_(r1, fmul_(w0.y, w0.y));
        r2 = fadd_(r2, fmul_(w0.z, w0.z));
        r3 = fadd_(r3, fmul_(w0.w, w0.w));
        r4 = fadd_(r4, fmul_(w1.x, w1.x));
        r5 = fadd_(r5, fmul_(w1.y, w1.y));
        r6 = fadd_(r6, fmul_(w1.z, w1.z));
        r7 = fadd_(r7, fmul_(w1.w, w1.w));
    }
    float s = fadd_(fadd_(fadd_(r0, r1), fadd_(r2, r3)),
                    fadd_(fadd_(r4, r5), fadd_(r6, r7)));
    float u = __shfl_down(s, 1, 64);
    float t = fadd_(s, u);
    float w = __shfl_down(t, 2, 64);
    float tot = fadd_(t, w);
    if (blk == 0) *outn = tot;
}

// ---------------------------------------------------------------- rownorm
// (kept for the fallback path; verified R2/R3)
__global__ void rownorm_np_kernel(const float* __restrict__ src, int nrows,
                                  float* __restrict__ out) {
    int gid = blockIdx.x * blockDim.x + threadIdx.x;
    int row = gid >> 2;
    int blk = gid & 3;
    if (row >= nrows) return;
    const float4* p = (const float4*)(src + (size_t)row * D_DIM + blk * 128);
    float4 v0 = p[0], v1 = p[1];
    float r0 = fmul_(v0.x, v0.x), r1 = fmul_(v0.y, v0.y);
    float r2 = fmul_(v0.z, v0.z), r3 = fmul_(v0.w, v0.w);
    float r4 = fmul_(v1.x, v1.x), r5 = fmul_(v1.y, v1.y);
    float r6 = fmul_(v1.z, v1.z), r7 = fmul_(v1.w, v1.w);
#pragma unroll
    for (int i = 1; i < 16; i++) {
        float4 w0 = p[2 * i], w1 = p[2 * i + 1];
        r0 = fadd_(r0, fmul_(w0.x, w0.x));
        r1 = fadd_(r1, fmul_(w0.y, w0.y));
        r2 = fadd_(r2, fmul_(w0.z, w0.z));
        r3 = fadd_(r3, fmul_(w0.w, w0.w));
        r4 = fadd_(r4, fmul_(w1.x, w1.x));
        r5 = fadd_(r5, fmul_(w1.y, w1.y));
        r6 = fadd_(r6, fmul_(w1.z, w1.z));
        r7 = fadd_(r7, fmul_(w1.w, w1.w));
    }
    float s = fadd_(fadd_(fadd_(r0, r1), fadd_(r2, r3)),
                    fadd_(fadd_(r4, r5), fadd_(r6, r7)));
    float u = __shfl_down(s, 1, 64);
    float t = fadd_(s, u);
    float w = __shfl_down(t, 2, 64);
    float tot = fadd_(t, w);
    if (blk == 0) out[row] = tot;
}

// ---------------------------------------------------------------- phase 1
// bf16 MFMA GEMM, fused epilogue. R8: DOUBLE-BUFFERED 2-STAGE PIPELINE.
// R7 post-mortem: halving barrier count bought only 6% -> cost is the
// per-round SERIAL {issue loads -> drain -> compute} latency (~2500 cyc/rnd
// vs ~620 cyc compute content; only 2 blocks/CU to overlap). Fix: stage
// slab dt+1 into buf^1 BEFORE computing slab dt from buf; the compiler's
// implicit vmcnt(0)-before-s_barrier then drains AFTER compute, so load
// latency hides under MFMA. One barrier/round. Hazards: STAGE(buf^1) WAR
// ok (last read at dt-1, behind that round's barrier); compute RAW ok
// (staged at dt-1, drained at its barrier); rowminU kt-ordering via the
// prologue barrier. Accumulation order & fragment addressing unchanged.
// LDS 66 KB -> still 2 blocks/CU (reg-limited anyway).
__global__ __launch_bounds__(512, 4) void score_gemm_kernel(
    const u16t* __restrict__ zb, const u16t* __restrict__ cbb,
    const float* __restrict__ cnorm,
    float* __restrict__ chunkmin,      // [N_ROWS][NCHUNK]
    uint32* __restrict__ cnts,         // [N_ROWS][NCHUNK]
    uint2* __restrict__ cand) {        // [N_ROWS][NCHUNK][CCAP] {sbits,k}
    __shared__ alignas(16) u16t Ab[2][128 * 64];   // 2 x 16 KB per operand
    __shared__ alignas(16) u16t Bb[2][128 * 64];
    __shared__ uint32 rowminU[128];    // running chunk min (monotone key)
    __shared__ int ccnt[128];          // per-row candidate count (this chunk)

    const int t = threadIdx.x;
    const int bx = blockIdx.x;
    const int by = blockIdx.y;
    const int row0 = by * 128, k0 = bx * KCHUNK;
    const int w = t >> 6, lane = t & 63;
    const int wx = w & 1, wy = w >> 1;           // wx: col half, wy: row quarter
    const int l15 = lane & 15, quad = lane >> 4;

    if (t < 128) { rowminU[t] = 0xFFFFFFFFu; ccnt[t] = 0; }
    // (ordered before first epilogue use by the kt-0 prologue barrier)

    for (int kt = 0; kt < 4; kt++) {
        f32x4 acc[2][4];
#pragma unroll
        for (int i = 0; i < 2; i++)
#pragma unroll
            for (int j = 0; j < 4; j++) acc[i][j] = (f32x4){0.f, 0.f, 0.f, 0.f};

        // per-thread global cursors (wave w stages rows w*16..w*16+15)
        const u16t* ga = zb + (size_t)(row0 + (t >> 2)) * D_DIM + (t & 3) * 8;
        const u16t* gb = cbb + (size_t)(k0 + kt * 128 + (t >> 2)) * D_DIM + (t & 3) * 8;

        // ---- prologue: stage slab 0 into buffer 0 ----
        {
            __builtin_amdgcn_global_load_lds(
                (const __attribute__((address_space(1))) void*)ga,
                (__attribute__((address_space(3))) void*)((char*)Ab[0] + w * 1024), 16, 0, 0);
            __builtin_amdgcn_global_load_lds(
                (const __attribute__((address_space(1))) void*)(ga + 32),
                (__attribute__((address_space(3))) void*)((char*)Ab[0] + 8192 + w * 1024), 16, 0, 0);
            __builtin_amdgcn_global_load_lds(
                (const __attribute__((address_space(1))) void*)gb,
                (__attribute__((address_space(3))) void*)((char*)Bb[0] + w * 1024), 16, 0, 0);
            __builtin_amdgcn_global_load_lds(
                (const __attribute__((address_space(1))) void*)(gb + 32),
                (__attribute__((address_space(3))) void*)((char*)Bb[0] + 8192 + w * 1024), 16, 0, 0);
            ga += 64; gb += 64;
        }
        __syncthreads();   // drain prologue loads (implicit vmcnt 0)

        for (int dt = 0; dt < 8; dt++) {          // 8 x 64-dim slabs
            const int cur = dt & 1;
            // ---- issue next slab's loads into the other buffer ----
            if (dt < 7) {
                const int nxt = cur ^ 1;
                __builtin_amdgcn_global_load_lds(
                    (const __attribute__((address_space(1))) void*)ga,
                    (__attribute__((address_space(3))) void*)((char*)Ab[nxt] + w * 1024), 16, 0, 0);
                __builtin_amdgcn_global_load_lds(
                    (const __attribute__((address_space(1))) void*)(ga + 32),
                    (__attribute__((address_space(3))) void*)((char*)Ab[nxt] + 8192 + w * 1024), 16, 0, 0);
                __builtin_amdgcn_global_load_lds(
                    (const __attribute__((address_space(1))) void*)gb,
                    (__attribute__((address_space(3))) void*)((char*)Bb[nxt] + w * 1024), 16, 0, 0);
                __builtin_amdgcn_global_load_lds(
                    (const __attribute__((address_space(1))) void*)(gb + 32),
                    (__attribute__((address_space(3))) void*)((char*)Bb[nxt] + 8192 + w * 1024), 16, 0, 0);
                ga += 64; gb += 64;
            }
            // ---- compute current slab while those loads fly ----
#pragma unroll
            for (int sub = 0; sub < 2; sub++) {
                short8 a[2];
#pragma unroll
                for (int i = 0; i < 2; i++)
                    a[i] = *(const short8*)((char*)Ab[cur] + sub * 8192 +
                                            (wy * 32 + i * 16 + l15) * 64 + quad * 16);
#pragma unroll
                for (int j = 0; j < 4; j++) {
                    short8 b = *(const short8*)((char*)Bb[cur] + sub * 8192 +
                                                (wx * 64 + j * 16 + l15) * 64 + quad * 16);
#pragma unroll
                    for (int i = 0; i < 2; i++)
                        acc[i][j] = __builtin_amdgcn_mfma_f32_16x16x32_bf16(a[i], b, acc[i][j], 0, 0, 0);
                }
            }
            __syncthreads();   // drains the prefetch (vmcnt 0) AFTER compute
        }

        // ---- fused epilogue ----
        float cnj[4];
#pragma unroll
        for (int j = 0; j < 4; j++)
            cnj[j] = cnorm[k0 + kt * 128 + wx * 64 + j * 16 + l15];

        // pass 1: per-row running min (per-thread j-min + DPP row-min)
#pragma unroll
        for (int i = 0; i < 2; i++) {
#pragma unroll
            for (int r = 0; r < 4; r++) {
                float m = fmaf(-2.f, acc[i][0][r], cnj[0]);
                m = fminf(m, fmaf(-2.f, acc[i][1][r], cnj[1]));
                m = fminf(m, fmaf(-2.f, acc[i][2][r], cnj[2]));
                m = fminf(m, fmaf(-2.f, acc[i][3][r], cnj[3]));
                m = dpp_min16(m);                 // min over the 16 l15 lanes
                if (l15 == 0)
                    atomicMin(&rowminU[wy * 32 + i * 16 + quad * 4 + r], fkey(m));
            }
        }
        __syncthreads();
        // pass 2: append candidates vs running-min threshold (superset-safe;
        // refine re-filters with the exact global min)
#pragma unroll
        for (int i = 0; i < 2; i++) {
#pragma unroll
            for (int r = 0; r < 4; r++) {
                const int rl = wy * 32 + i * 16 + quad * 4 + r;
                const float thr = fdec(rowminU[rl]) + MARGIN;
#pragma unroll
                for (int j = 0; j < 4; j++) {
                    float s = fmaf(-2.f, acc[i][j][r], cnj[j]);
                    if (s <= thr) {
                        int pos = atomicAdd(&ccnt[rl], 1);
                        if (pos < CCAP) {
                            uint2 e;
                            e.x = __float_as_uint(s);
                            e.y = (uint32)(k0 + kt * 128 + wx * 64 + j * 16 + l15);
                            cand[((size_t)(row0 + rl) * NCHUNK + bx) * CCAP + pos] = e;
                        }
                    }
                }
            }
        }
        // next kt's prologue __syncthreads orders pass2 reads of rowminU
        // before the next kt's pass-1 atomicMin updates
    }
    __syncthreads();
    if (t < 128) {
        chunkmin[(size_t)(row0 + t) * NCHUNK + bx] = fdec(rowminU[t]);
        int c = ccnt[t];
        cnts[(size_t)(row0 + t) * NCHUNK + bx] = (uint32)(c < CCAP ? c : CCAP);
    }
}

// ---------------------------------------------------------------- phase 2
// ONE WAVE PER ROW, zero barriers, zero LDS (verified R6 structure).
__global__ __launch_bounds__(256) void refine_kernel(
    const uint2* __restrict__ cand, const uint32* __restrict__ cnts,
    const float* __restrict__ chunkmin,
    const float* __restrict__ z, const float* __restrict__ cb,
    const float* __restrict__ zz, const float* __restrict__ cnorm,
    float* __restrict__ out_zq, float* __restrict__ out_idx,
    float* __restrict__ rowsum) {
    const int t = threadIdx.x;
    const int wid = t >> 6, lane = t & 63;
    const int row = blockIdx.x * 4 + wid;

    // global coarse min over the 8 chunk minima (fminf is order-independent)
    float cm = chunkmin[(size_t)row * NCHUNK + (lane & 7)];
    cm = fminf(cm, __shfl_xor(cm, 1, 64));
    cm = fminf(cm, __shfl_xor(cm, 2, 64));
    cm = fminf(cm, __shfl_xor(cm, 4, 64));
    const float thr = cm + MARGIN;

    // z row into regs (verified layout: lane covers elements lane*8..lane*8+7)
    const float* zr = z + (size_t)row * D_DIM;
    float4 z0 = *(const float4*)(zr + lane * 8);
    float4 z1 = *(const float4*)(zr + lane * 8 + 4);
    const float zzr = zz[row];

    float bv = 3.4e38f;
    int bi = 0x7fffffff;
#pragma unroll
    for (int it = 0; it < (NCHUNK * CCAP) / 64; ++it) {
        int idx = it * 64 + lane;
        int c = idx >> 5, s2 = idx & (CCAP - 1);
        uint32 n = cnts[(size_t)row * NCHUNK + c];
        int kk = -1;
        if ((uint32)s2 < n) {
            uint2 e = cand[((size_t)row * NCHUNK + c) * CCAP + s2];
            if (__uint_as_float(e.x) <= thr) kk = (int)e.y;
        }
        unsigned long long mask = __ballot(kk >= 0);
        while (mask) {
            int src = __ffsll((unsigned long long)mask) - 1;
            mask &= (mask - 1);
            int k = __shfl(kk, src, 64);
            // exact np-fp32 dist (verified R3 instruction sequence)
            const float* cr = cb + (size_t)k * D_DIM;
            float4 c0 = *(const float4*)(cr + lane * 8);
            float4 c1 = *(const float4*)(cr + lane * 8 + 4);
            float d = fmul_(z0.x, c0.x);
            d = fmaf(z0.y, c0.y, d); d = fmaf(z0.z, c0.z, d); d = fmaf(z0.w, c0.w, d);
            d = fmaf(z1.x, c1.x, d); d = fmaf(z1.y, c1.y, d);
            d = fmaf(z1.z, c1.z, d); d = fmaf(z1.w, c1.w, d);
#pragma unroll
            for (int off = 1; off < 64; off <<= 1)
                d = fadd_(d, __shfl_xor(d, off, 64));
            float dist = fmaf(-2.f, d, fadd_(zzr, cnorm[k]));
            // (value, index) tie-break; wave-uniform after the full reduce
            if (dist < bv || (dist == bv && k < bi)) { bv = dist; bi = k; }
        }
    }
    // defensive clamp: never let a pathological empty list read OOB
    if (bi == 0x7fffffff) bi = 0;
    if (lane == 0) out_idx[row] = (float)bi;

    // STE + rowsum (verified bit-exact tree via lane-leaf layout)
    const float* cq = cb + (size_t)bi * D_DIM;
    float v[4];
#pragma unroll
    for (int q = 0; q < 4; q++) {
        const int off = q * 128 + lane * 2;
        float2 zv2 = *(const float2*)(zr + off);
        float2 cv2 = *(const float2*)(cq + off);
        float2 o;
        o.x = fadd_(zv2.x, __fsub_rn(cv2.x, zv2.x));
        o.y = fadd_(zv2.y, __fsub_rn(cv2.y, zv2.y));
        *(float2*)(out_zq + (size_t)row * D_DIM + off) = o;
        float dx = zv2.x - cv2.x, dy = zv2.y - cv2.y;
        v[q] = dx * dx + dy * dy;
    }
    float s = fadd_(fadd_(v[0], v[2]), fadd_(v[1], v[3]));
    s = fadd_(s, __shfl_down(s, 32, 64));
    s = fadd_(s, __shfl_down(s, 16, 64));
    s = fadd_(s, __shfl_down(s, 8, 64));
    s = fadd_(s, __shfl_down(s, 4, 64));
    s = fadd_(s, __shfl_down(s, 2, 64));
    s = fadd_(s, __shfl_down(s, 1, 64));
    if (lane == 0) rowsum[row] = s;
}

// ---------------------------------------------------------------- loss
__global__ void loss_kernel(const float* __restrict__ rowsum,
                            float* __restrict__ out_loss) {
    __shared__ float sm[256];
    float s = 0.f;
    for (int i = threadIdx.x; i < N_ROWS; i += 256) s += rowsum[i];
    sm[threadIdx.x] = s;
    __syncthreads();
    for (int st = 128; st; st >>= 1) {
        if (threadIdx.x < st) sm[threadIdx.x] += sm[threadIdx.x + st];
        __syncthreads();
    }
    if (threadIdx.x == 0)
        *out_loss = 1.25f * sm[0] / (float)(N_ROWS * D_DIM);
}

// ================================================================ fallback
// (verified round-2 fp32 path, used only if ws_size too small)
#define BM 128
#define BN 128
#define BK 16
#define TM 8
#define TN 8

__global__ __launch_bounds__(256, 4) void vq_argmin_kernel(
    const float* __restrict__ z, const float* __restrict__ cb,
    const float* __restrict__ zz, const float* __restrict__ cnorm,
    float* __restrict__ pval, int* __restrict__ pidx) {
    __shared__ float As[BK][BM + 4];
    __shared__ float Bs[BK][BN + 4];
    __shared__ float rv[BM][17];
    __shared__ int   ri[BM][17];

    const int bx = blockIdx.x;
    const int by = blockIdx.y;
    const int row0 = by * BM;
    const int k0 = bx * KCHUNK;
    const int t = threadIdx.x;
    const int tx = t & 15;
    const int ty = t >> 4;

    float minv[TM];
    int   mini[TM];
#pragma unroll
    for (int i = 0; i < TM; i++) { minv[i] = 3.4e38f; mini[i] = 0; }
    float zrow[TM];
#pragma unroll
    for (int i = 0; i < TM; i++) zrow[i] = zz[row0 + ty * TM + i];
    const int sr = t >> 1;
    const int sdq = (t & 1) * 8;

    for (int kt = 0; kt < KCHUNK / BN; kt++) {
        const int col0 = k0 + kt * BN;
        float acc[TM][TN];
#pragma unroll
        for (int i = 0; i < TM; i++)
#pragma unroll
            for (int j = 0; j < TN; j++) acc[i][j] = 0.f;
        for (int dt = 0; dt < D_DIM; dt += BK) {
            {
                const float* src = z + (size_t)(row0 + sr) * D_DIM + dt + sdq;
                float4 v0 = *(const float4*)(src);
                float4 v1 = *(const float4*)(src + 4);
                As[sdq + 0][sr] = v0.x; As[sdq + 1][sr] = v0.y;
                As[sdq + 2][sr] = v0.z; As[sdq + 3][sr] = v0.w;
                As[sdq + 4][sr] = v1.x; As[sdq + 5][sr] = v1.y;
                As[sdq + 6][sr] = v1.z; As[sdq + 7][sr] = v1.w;
                const float* srcb = cb + (size_t)(col0 + sr) * D_DIM + dt + sdq;
                float4 w0 = *(const float4*)(srcb);
                float4 w1 = *(const float4*)(srcb + 4);
                Bs[sdq + 0][sr] = w0.x; Bs[sdq + 1][sr] = w0.y;
                Bs[sdq + 2][sr] = w0.z; Bs[sdq + 3][sr] = w0.w;
                Bs[sdq + 4][sr] = w1.x; Bs[sdq + 5][sr] = w1.y;
                Bs[sdq + 6][sr] = w1.z; Bs[sdq + 7][sr] = w1.w;
            }
            __syncthreads();
#pragma unroll
            for (int d = 0; d < BK; d++) {
                float a[TM], b[TN];
#pragma unroll
                for (int i = 0; i < TM; i++) a[i] = As[d][ty * TM + i];
#pragma unroll
                for (int j = 0; j < TN; j++) b[j] = Bs[d][tx * TN + j];
#pragma unroll
                for (int i = 0; i < TM; i++)
#pragma unroll
                    for (int j = 0; j < TN; j++)
                        acc[i][j] = fmaf(a[i], b[j], acc[i][j]);
            }
            __syncthreads();
        }
#pragma unroll
        for (int j = 0; j < TN; j++) {
            const int col = col0 + tx * TN + j;
            const float cn = cnorm[col];
#pragma unroll
            for (int i = 0; i < TM; i++) {
                float s1 = fadd_(zrow[i], cn);
                float s = fmaf(-2.f, acc[i][j], s1);
                if (s < minv[i]) { minv[i] = s; mini[i] = col; }
            }
        }
    }
#pragma unroll
    for (int i = 0; i < TM; i++) {
        rv[ty * TM + i][tx] = minv[i];
        ri[ty * TM + i][tx] = mini[i];
    }
    __syncthreads();
    if (t < BM) {
        float bv = rv[t][0];
        int   bi = ri[t][0];
#pragma unroll
        for (int x = 1; x < 16; x++) {
            float v = rv[t][x]; int ii = ri[t][x];
            if (v < bv || (v == bv && ii < bi)) { bv = v; bi = ii; }
        }
        pval[(size_t)(row0 + t) * NCHUNK + bx] = bv;
        pidx[(size_t)(row0 + t) * NCHUNK + bx] = bi;
    }
}

__global__ void finalize_kernel(const float* __restrict__ z,
                                const float* __restrict__ cb,
                                const float* __restrict__ pval,
                                const int* __restrict__ pidx,
                                float* __restrict__ out_zq,
                                float* __restrict__ out_idx,
                                float* __restrict__ rowsum) {
    int row = (blockIdx.x * blockDim.x + threadIdx.x) >> 6;
    int lane = threadIdx.x & 63;
    if (row >= N_ROWS) return;
    float bv = pval[(size_t)row * NCHUNK];
    int   bi = pidx[(size_t)row * NCHUNK];
#pragma unroll
    for (int c = 1; c < NCHUNK; c++) {
        float v = pval[(size_t)row * NCHUNK + c];
        int  ii = pidx[(size_t)row * NCHUNK + c];
        if (v < bv || (v == bv && ii < bi)) { bv = v; bi = ii; }
    }
    const float4* zr = (const float4*)(z + (size_t)row * D_DIM);
    const float4* cr = (const float4*)(cb + (size_t)bi * D_DIM);
    float4* orow = (float4*)(out_zq + (size_t)row * D_DIM);
    float s = 0.f;
#pragma unroll
    for (int i = 0; i < 2; i++) {
        float4 zv = zr[i * 64 + lane];
        float4 cv = cr[i * 64 + lane];
        float4 o;
        o.x = fadd_(zv.x, __fsub_rn(cv.x, zv.x));
        o.y = fadd_(zv.y, __fsub_rn(cv.y, zv.y));
        o.z = fadd_(zv.z, __fsub_rn(cv.z, zv.z));
        o.w = fadd_(zv.w, __fsub_rn(cv.w, zv.w));
        orow[i * 64 + lane] = o;
        float dx = zv.x - cv.x, dy = zv.y - cv.y;
        float dz = zv.z - cv.z, dw = zv.w - cv.w;
        s += dx * dx + dy * dy + dz * dz + dw * dw;
    }
#pragma unroll
    for (int off = 32; off; off >>= 1) s += __shfl_down(s, off, 64);
    if (lane == 0) {
        rowsum[row] = s;
        out_idx[row] = (float)bi;
    }
}

// ---------------------------------------------------------------- launch
extern "C" void kernel_launch(void* const* d_in, const int* in_sizes, int n_in,
                              void* d_out, int out_size, void* d_ws, size_t ws_size,
                              hipStream_t stream) {
    const float* z  = (const float*)d_in[0];
    const float* cb = (const float*)d_in[1];
    float* out      = (float*)d_out;
    float* out_zq   = out;
    float* out_idx  = out + (size_t)N_ROWS * D_DIM;
    float* out_loss = out_idx + N_ROWS;

    float* zz     = (float*)d_ws;                          // 16384 f32
    float* cnorm  = zz + N_ROWS;                           // 4096 f32
    float* rowsum = cnorm + K_CODES;                       // 16384 f32
    u16t*  z_bf   = (u16t*)(rowsum + N_ROWS);              // 16384*512 u16
    u16t*  cb_bf  = z_bf + (size_t)N_ROWS * D_DIM;         // 4096*512 u16
    float* chunkmin = (float*)(cb_bf + (size_t)K_CODES * D_DIM);   // 16384*8 f32
    uint32* cnts  = (uint32*)(chunkmin + (size_t)N_ROWS * NCHUNK); // 16384*8 u32
    uint2* cand   = (uint2*)(cnts + (size_t)N_ROWS * NCHUNK);      // 16384*8*32 uint2
    const size_t WS_NEEDED = (size_t)(N_ROWS + K_CODES + N_ROWS) * 4
                           + (size_t)N_ROWS * D_DIM * 2
                           + (size_t)K_CODES * D_DIM * 2
                           + (size_t)N_ROWS * NCHUNK * 4 * 2
                           + (size_t)N_ROWS * NCHUNK * CCAP * 8;

    if (ws_size >= WS_NEEDED) {
        prep_kernel<<<((N_ROWS + K_CODES) * 4) / 256, 256, 0, stream>>>(
            z, cb, z_bf, cb_bf, zz, cnorm);

        dim3 g1(NCHUNK, N_ROWS / 128);
        score_gemm_kernel<<<g1, 512, 0, stream>>>(z_bf, cb_bf, cnorm,
                                                  chunkmin, cnts, cand);
        refine_kernel<<<N_ROWS / 4, 256, 0, stream>>>(cand, cnts, chunkmin,
                                                      z, cb, zz, cnorm,
                                                      out_zq, out_idx, rowsum);
        loss_kernel<<<1, 256, 0, stream>>>(rowsum, out_loss);
    } else {
        // fallback: verified round-2 fp32 path (~1 MB ws)
        float* pval = rowsum + N_ROWS;
        int*   pidx = (int*)(pval + (size_t)N_ROWS * NCHUNK);
        rownorm_np_kernel<<<(N_ROWS * 4) / 256, 256, 0, stream>>>(z, N_ROWS, zz);
        rownorm_np_kernel<<<(K_CODES * 4) / 256, 256, 0, stream>>>(cb, K_CODES, cnorm);
        dim3 g2(NCHUNK, N_ROWS / BM);
        vq_argmin_kernel<<<g2, 256, 0, stream>>>(z, cb, zz, cnorm, pval, pidx);
        finalize_kernel<<<N_ROWS / 4, 256, 0, stream>>>(z, cb, pval, pidx,
                                                        out_zq, out_idx, rowsum);
        loss_kernel<<<1, 256, 0, stream>>>(rowsum, out_loss);
    }
}

// Round 9
// 262.096 us; speedup vs baseline: 1.1154x; 1.1154x over previous
//
#include <hip/hip_runtime.h>
#include <math.h>

#define N_ROWS 16384
#define K_CODES 4096
#define D_DIM 512
#define NCHUNK 8
#define KCHUNK (K_CODES / NCHUNK)
#define MARGIN 2.5e-3f
#define CCAP 32   // per-row per-chunk candidate cap (expected ~1-4 used)

typedef unsigned int uint32;
typedef unsigned short u16t;
typedef __attribute__((ext_vector_type(8))) short short8;
typedef __attribute__((ext_vector_type(4))) float f32x4;

__device__ __forceinline__ float fmul_(float a, float b) { return __fmul_rn(a, b); }
__device__ __forceinline__ float fadd_(float a, float b) { return __fadd_rn(a, b); }

// ---------------------------------------------------------------- cvt bf16
__device__ __forceinline__ u16t f2bf(float x) {
    uint32 u = __float_as_uint(x);
    return (u16t)((u + 0x7fffu + ((u >> 16) & 1u)) >> 16);   // RNE
}
// order-preserving float<->uint key for LDS atomicMin on floats (incl. negatives)
__device__ __forceinline__ uint32 fkey(float f) {
    uint32 u = __float_as_uint(f);
    return (u & 0x80000000u) ? ~u : (u | 0x80000000u);
}
__device__ __forceinline__ float fdec(uint32 k) {
    uint32 u = (k & 0x80000000u) ? (k ^ 0x80000000u) : ~k;
    return __uint_as_float(u);
}
// min across each contiguous 16-lane group, pure-VALU DPP (no ds_swizzle).
__device__ __forceinline__ float dpp_min16(float x) {
    int y;
    y = __builtin_amdgcn_update_dpp(0, __float_as_int(x), 0xB1, 0xf, 0xf, true);
    x = fminf(x, __int_as_float(y));
    y = __builtin_amdgcn_update_dpp(0, __float_as_int(x), 0x4E, 0xf, 0xf, true);
    x = fminf(x, __int_as_float(y));
    y = __builtin_amdgcn_update_dpp(0, __float_as_int(x), 0x141, 0xf, 0xf, true);
    x = fminf(x, __int_as_float(y));
    y = __builtin_amdgcn_update_dpp(0, __float_as_int(x), 0x140, 0xf, 0xf, true);
    x = fminf(x, __int_as_float(y));
    return x;
}

// ---------------------------------------------------------------- prep
// FUSED cvt_bf16 + rownorm (verified R7): reads each input once, row-norm
// arithmetic byte-identical to the verified rownorm_np_kernel.
__global__ void prep_kernel(const float* __restrict__ z,
                            const float* __restrict__ cb,
                            u16t* __restrict__ z_bf, u16t* __restrict__ cb_bf,
                            float* __restrict__ zz, float* __restrict__ cnorm) {
    int gid = blockIdx.x * blockDim.x + threadIdx.x;
    int row = gid >> 2;
    int blk = gid & 3;
    const float* src;
    u16t* dst;
    float* outn;
    if (row < N_ROWS) {
        src = z + (size_t)row * D_DIM;
        dst = z_bf + (size_t)row * D_DIM;
        outn = zz + row;
    } else {
        int r = row - N_ROWS;
        if (r >= K_CODES) return;
        src = cb + (size_t)r * D_DIM;
        dst = cb_bf + (size_t)r * D_DIM;
        outn = cnorm + r;
    }
    const float4* p = (const float4*)(src + blk * 128);
    u16t* d = dst + blk * 128;
    float4 v0 = p[0], v1 = p[1];
    {
        short8 o;
        o[0] = (short)f2bf(v0.x); o[1] = (short)f2bf(v0.y);
        o[2] = (short)f2bf(v0.z); o[3] = (short)f2bf(v0.w);
        o[4] = (short)f2bf(v1.x); o[5] = (short)f2bf(v1.y);
        o[6] = (short)f2bf(v1.z); o[7] = (short)f2bf(v1.w);
        *(short8*)d = o;
    }
    float r0 = fmul_(v0.x, v0.x), r1 = fmul_(v0.y, v0.y);
    float r2 = fmul_(v0.z, v0.z), r3 = fmul_(v0.w, v0.w);
    float r4 = fmul_(v1.x, v1.x), r5 = fmul_(v1.y, v1.y);
    float r6 = fmul_(v1.z, v1.z), r7 = fmul_(v1.w, v1.w);
#pragma unroll
    for (int i = 1; i < 16; i++) {
        float4 w0 = p[2 * i], w1 = p[2 * i + 1];
        {
            short8 o;
            o[0] = (short)f2bf(w0.x); o[1] = (short)f2bf(w0.y);
            o[2] = (short)f2bf(w0.z); o[3] = (short)f2bf(w0.w);
            o[4] = (short)f2bf(w1.x); o[5] = (short)f2bf(w1.y);
            o[6] = (short)f2bf(w1.z); o[7] = (short)f2bf(w1.w);
            *(short8*)(d + i * 8) = o;
        }
        r0 = fadd_(r0, fmul_(w0.x, w0.x));
        r1 = fadd_(r1, fmul_(w0.y, w0.y));
        r2 = fadd_(r2, fmul_(w0.z, w0.z));
        r3 = fadd_(r3, fmul_(w0.w, w0.w));
        r4 = fadd_(r4, fmul_(w1.x, w1.x));
        r5 = fadd_(r5, fmul_(w1.y, w1.y));
        r6 = fadd_(r6, fmul_(w1.z, w1.z));
        r7 = fadd_(r7, fmul_(w1.w, w1.w));
    }
    float s = fadd_(fadd_(fadd_(r0, r1), fadd_(r2, r3)),
                    fadd_(fadd_(r4, r5), fadd_(r6, r7)));
    float u = __shfl_down(s, 1, 64);
    float t = fadd_(s, u);
    float w = __shfl_down(t, 2, 64);
    float tot = fadd_(t, w);
    if (blk == 0) *outn = tot;
}

// ---------------------------------------------------------------- rownorm
// (kept for the fallback path; verified R2/R3)
__global__ void rownorm_np_kernel(const float* __restrict__ src, int nrows,
                                  float* __restrict__ out) {
    int gid = blockIdx.x * blockDim.x + threadIdx.x;
    int row = gid >> 2;
    int blk = gid & 3;
    if (row >= nrows) return;
    const float4* p = (const float4*)(src + (size_t)row * D_DIM + blk * 128);
    float4 v0 = p[0], v1 = p[1];
    float r0 = fmul_(v0.x, v0.x), r1 = fmul_(v0.y, v0.y);
    float r2 = fmul_(v0.z, v0.z), r3 = fmul_(v0.w, v0.w);
    float r4 = fmul_(v1.x, v1.x), r5 = fmul_(v1.y, v1.y);
    float r6 = fmul_(v1.z, v1.z), r7 = fmul_(v1.w, v1.w);
#pragma unroll
    for (int i = 1; i < 16; i++) {
        float4 w0 = p[2 * i], w1 = p[2 * i + 1];
        r0 = fadd_(r0, fmul_(w0.x, w0.x));
        r1 = fadd_(r1, fmul_(w0.y, w0.y));
        r2 = fadd_(r2, fmul_(w0.z, w0.z));
        r3 = fadd_(r3, fmul_(w0.w, w0.w));
        r4 = fadd_(r4, fmul_(w1.x, w1.x));
        r5 = fadd_(r5, fmul_(w1.y, w1.y));
        r6 = fadd_(r6, fmul_(w1.z, w1.z));
        r7 = fadd_(r7, fmul_(w1.w, w1.w));
    }
    float s = fadd_(fadd_(fadd_(r0, r1), fadd_(r2, r3)),
                    fadd_(fadd_(r4, r5), fadd_(r6, r7)));
    float u = __shfl_down(s, 1, 64);
    float t = fadd_(s, u);
    float w = __shfl_down(t, 2, 64);
    float tot = fadd_(t, w);
    if (blk == 0) out[row] = tot;
}

// ---------------------------------------------------------------- phase 1
// bf16 MFMA GEMM, fused epilogue. R9: R7's verified single-buffer BK=64
// structure (R8's explicit double-buffer reverted: implicit vmcnt(0) at
// every barrier drains the prefetch too -> known-null + traffic regression),
// PLUS XCD-locality grid transpose. R7 moved 281 MB of L2-miss traffic for
// 20 MB of data: with grid(8,128), XCD = bid%8 = bx, so every XCD streamed
// all 16 MB of z through its 4 MB L2 (64 concurrent 131 KB panels evict
// between kt re-reads). Grid(128,8) makes XCD = panel%8: each XCD keeps its
// 16 z-panels (2 MB) L2-resident for the whole kernel and streams cb chunks
// (0.5 MB) once each. Predicted FETCH 281 -> 60-110 MB.
__global__ __launch_bounds__(512, 4) void score_gemm_kernel(
    const u16t* __restrict__ zb, const u16t* __restrict__ cbb,
    const float* __restrict__ cnorm,
    float* __restrict__ chunkmin,      // [N_ROWS][NCHUNK]
    uint32* __restrict__ cnts,         // [N_ROWS][NCHUNK]
    uint2* __restrict__ cand) {        // [N_ROWS][NCHUNK][CCAP] {sbits,k}
    __shared__ alignas(16) u16t Ab[128 * 64];   // [2][128][32] bf16, 16 KB
    __shared__ alignas(16) u16t Bb[128 * 64];
    __shared__ uint32 rowminU[128];    // running chunk min (monotone key)
    __shared__ int ccnt[128];          // per-row candidate count (this chunk)

    const int t = threadIdx.x;
    const int panel = blockIdx.x;      // row-panel index (XCD = panel % 8)
    const int chunk = blockIdx.y;      // codebook chunk index
    const int row0 = panel * 128, k0 = chunk * KCHUNK;
    const int w = t >> 6, lane = t & 63;
    const int wx = w & 1, wy = w >> 1;           // wx: col half, wy: row quarter
    const int l15 = lane & 15, quad = lane >> 4;

    if (t < 128) { rowminU[t] = 0xFFFFFFFFu; ccnt[t] = 0; }
    // (ordered before first use by the dt-loop's leading __syncthreads)

    for (int kt = 0; kt < 4; kt++) {
        f32x4 acc[2][4];
#pragma unroll
        for (int i = 0; i < 2; i++)
#pragma unroll
            for (int j = 0; j < 4; j++) acc[i][j] = (f32x4){0.f, 0.f, 0.f, 0.f};

        // per-thread global cursors (wave w stages rows w*16..w*16+15)
        const u16t* ga = zb + (size_t)(row0 + (t >> 2)) * D_DIM + (t & 3) * 8;
        const u16t* gb = cbb + (size_t)(k0 + kt * 128 + (t >> 2)) * D_DIM + (t & 3) * 8;

        for (int dt = 0; dt < 8; dt++) {          // 8 x 64-dim slabs
            __syncthreads();
            // sub0 (dims +0..31) and sub1 (dims +32..63) of both operands
            __builtin_amdgcn_global_load_lds(
                (const __attribute__((address_space(1))) void*)ga,
                (__attribute__((address_space(3))) void*)((char*)Ab + w * 1024),
                16, 0, 0);
            __builtin_amdgcn_global_load_lds(
                (const __attribute__((address_space(1))) void*)(ga + 32),
                (__attribute__((address_space(3))) void*)((char*)Ab + 8192 + w * 1024),
                16, 0, 0);
            __builtin_amdgcn_global_load_lds(
                (const __attribute__((address_space(1))) void*)gb,
                (__attribute__((address_space(3))) void*)((char*)Bb + w * 1024),
                16, 0, 0);
            __builtin_amdgcn_global_load_lds(
                (const __attribute__((address_space(1))) void*)(gb + 32),
                (__attribute__((address_space(3))) void*)((char*)Bb + 8192 + w * 1024),
                16, 0, 0);
            ga += 64; gb += 64;
            __syncthreads();
#pragma unroll
            for (int sub = 0; sub < 2; sub++) {
                short8 a[2];
#pragma unroll
                for (int i = 0; i < 2; i++)
                    a[i] = *(const short8*)((char*)Ab + sub * 8192 +
                                            (wy * 32 + i * 16 + l15) * 64 + quad * 16);
#pragma unroll
                for (int j = 0; j < 4; j++) {
                    short8 b = *(const short8*)((char*)Bb + sub * 8192 +
                                                (wx * 64 + j * 16 + l15) * 64 + quad * 16);
#pragma unroll
                    for (int i = 0; i < 2; i++)
                        acc[i][j] = __builtin_amdgcn_mfma_f32_16x16x32_bf16(a[i], b, acc[i][j], 0, 0, 0);
                }
            }
        }

        // ---- fused epilogue ----
        float cnj[4];
#pragma unroll
        for (int j = 0; j < 4; j++)
            cnj[j] = cnorm[k0 + kt * 128 + wx * 64 + j * 16 + l15];

        // pass 1: per-row running min (per-thread j-min + DPP row-min)
#pragma unroll
        for (int i = 0; i < 2; i++) {
#pragma unroll
            for (int r = 0; r < 4; r++) {
                float m = fmaf(-2.f, acc[i][0][r], cnj[0]);
                m = fminf(m, fmaf(-2.f, acc[i][1][r], cnj[1]));
                m = fminf(m, fmaf(-2.f, acc[i][2][r], cnj[2]));
                m = fminf(m, fmaf(-2.f, acc[i][3][r], cnj[3]));
                m = dpp_min16(m);                 // min over the 16 l15 lanes
                if (l15 == 0)
                    atomicMin(&rowminU[wy * 32 + i * 16 + quad * 4 + r], fkey(m));
            }
        }
        __syncthreads();
        // pass 2: append candidates vs running-min threshold (superset-safe;
        // refine re-filters with the exact global min)
#pragma unroll
        for (int i = 0; i < 2; i++) {
#pragma unroll
            for (int r = 0; r < 4; r++) {
                const int rl = wy * 32 + i * 16 + quad * 4 + r;
                const float thr = fdec(rowminU[rl]) + MARGIN;
#pragma unroll
                for (int j = 0; j < 4; j++) {
                    float s = fmaf(-2.f, acc[i][j][r], cnj[j]);
                    if (s <= thr) {
                        int pos = atomicAdd(&ccnt[rl], 1);
                        if (pos < CCAP) {
                            uint2 e;
                            e.x = __float_as_uint(s);
                            e.y = (uint32)(k0 + kt * 128 + wx * 64 + j * 16 + l15);
                            cand[((size_t)(row0 + rl) * NCHUNK + chunk) * CCAP + pos] = e;
                        }
                    }
                }
            }
        }
        // next kt's dt-loop leading __syncthreads orders pass2 reads of
        // rowminU before the next kt's atomicMin updates
    }
    __syncthreads();
    if (t < 128) {
        chunkmin[(size_t)(row0 + t) * NCHUNK + chunk] = fdec(rowminU[t]);
        int c = ccnt[t];
        cnts[(size_t)(row0 + t) * NCHUNK + chunk] = (uint32)(c < CCAP ? c : CCAP);
    }
}

// ---------------------------------------------------------------- phase 2
// ONE WAVE PER ROW, zero barriers, zero LDS (verified R6 structure).
__global__ __launch_bounds__(256) void refine_kernel(
    const uint2* __restrict__ cand, const uint32* __restrict__ cnts,
    const float* __restrict__ chunkmin,
    const float* __restrict__ z, const float* __restrict__ cb,
    const float* __restrict__ zz, const float* __restrict__ cnorm,
    float* __restrict__ out_zq, float* __restrict__ out_idx,
    float* __restrict__ rowsum) {
    const int t = threadIdx.x;
    const int wid = t >> 6, lane = t & 63;
    const int row = blockIdx.x * 4 + wid;

    // global coarse min over the 8 chunk minima (fminf is order-independent)
    float cm = chunkmin[(size_t)row * NCHUNK + (lane & 7)];
    cm = fminf(cm, __shfl_xor(cm, 1, 64));
    cm = fminf(cm, __shfl_xor(cm, 2, 64));
    cm = fminf(cm, __shfl_xor(cm, 4, 64));
    const float thr = cm + MARGIN;

    // z row into regs (verified layout: lane covers elements lane*8..lane*8+7)
    const float* zr = z + (size_t)row * D_DIM;
    float4 z0 = *(const float4*)(zr + lane * 8);
    float4 z1 = *(const float4*)(zr + lane * 8 + 4);
    const float zzr = zz[row];

    float bv = 3.4e38f;
    int bi = 0x7fffffff;
#pragma unroll
    for (int it = 0; it < (NCHUNK * CCAP) / 64; ++it) {
        int idx = it * 64 + lane;
        int c = idx >> 5, s2 = idx & (CCAP - 1);
        uint32 n = cnts[(size_t)row * NCHUNK + c];
        int kk = -1;
        if ((uint32)s2 < n) {
            uint2 e = cand[((size_t)row * NCHUNK + c) * CCAP + s2];
            if (__uint_as_float(e.x) <= thr) kk = (int)e.y;
        }
        unsigned long long mask = __ballot(kk >= 0);
        while (mask) {
            int src = __ffsll((unsigned long long)mask) - 1;
            mask &= (mask - 1);
            int k = __shfl(kk, src, 64);
            // exact np-fp32 dist (verified R3 instruction sequence)
            const float* cr = cb + (size_t)k * D_DIM;
            float4 c0 = *(const float4*)(cr + lane * 8);
            float4 c1 = *(const float4*)(cr + lane * 8 + 4);
            float d = fmul_(z0.x, c0.x);
            d = fmaf(z0.y, c0.y, d); d = fmaf(z0.z, c0.z, d); d = fmaf(z0.w, c0.w, d);
            d = fmaf(z1.x, c1.x, d); d = fmaf(z1.y, c1.y, d);
            d = fmaf(z1.z, c1.z, d); d = fmaf(z1.w, c1.w, d);
#pragma unroll
            for (int off = 1; off < 64; off <<= 1)
                d = fadd_(d, __shfl_xor(d, off, 64));
            float dist = fmaf(-2.f, d, fadd_(zzr, cnorm[k]));
            // (value, index) tie-break; wave-uniform after the full reduce
            if (dist < bv || (dist == bv && k < bi)) { bv = dist; bi = k; }
        }
    }
    // defensive clamp: never let a pathological empty list read OOB
    if (bi == 0x7fffffff) bi = 0;
    if (lane == 0) out_idx[row] = (float)bi;

    // STE + rowsum (verified bit-exact tree via lane-leaf layout)
    const float* cq = cb + (size_t)bi * D_DIM;
    float v[4];
#pragma unroll
    for (int q = 0; q < 4; q++) {
        const int off = q * 128 + lane * 2;
        float2 zv2 = *(const float2*)(zr + off);
        float2 cv2 = *(const float2*)(cq + off);
        float2 o;
        o.x = fadd_(zv2.x, __fsub_rn(cv2.x, zv2.x));
        o.y = fadd_(zv2.y, __fsub_rn(cv2.y, zv2.y));
        *(float2*)(out_zq + (size_t)row * D_DIM + off) = o;
        float dx = zv2.x - cv2.x, dy = zv2.y - cv2.y;
        v[q] = dx * dx + dy * dy;
    }
    float s = fadd_(fadd_(v[0], v[2]), fadd_(v[1], v[3]));
    s = fadd_(s, __shfl_down(s, 32, 64));
    s = fadd_(s, __shfl_down(s, 16, 64));
    s = fadd_(s, __shfl_down(s, 8, 64));
    s = fadd_(s, __shfl_down(s, 4, 64));
    s = fadd_(s, __shfl_down(s, 2, 64));
    s = fadd_(s, __shfl_down(s, 1, 64));
    if (lane == 0) rowsum[row] = s;
}

// ---------------------------------------------------------------- loss
__global__ void loss_kernel(const float* __restrict__ rowsum,
                            float* __restrict__ out_loss) {
    __shared__ float sm[256];
    float s = 0.f;
    for (int i = threadIdx.x; i < N_ROWS; i += 256) s += rowsum[i];
    sm[threadIdx.x] = s;
    __syncthreads();
    for (int st = 128; st; st >>= 1) {
        if (threadIdx.x < st) sm[threadIdx.x] += sm[threadIdx.x + st];
        __syncthreads();
    }
    if (threadIdx.x == 0)
        *out_loss = 1.25f * sm[0] / (float)(N_ROWS * D_DIM);
}

// ================================================================ fallback
// (verified round-2 fp32 path, used only if ws_size too small)
#define BM 128
#define BN 128
#define BK 16
#define TM 8
#define TN 8

__global__ __launch_bounds__(256, 4) void vq_argmin_kernel(
    const float* __restrict__ z, const float* __restrict__ cb,
    const float* __restrict__ zz, const float* __restrict__ cnorm,
    float* __restrict__ pval, int* __restrict__ pidx) {
    __shared__ float As[BK][BM + 4];
    __shared__ float Bs[BK][BN + 4];
    __shared__ float rv[BM][17];
    __shared__ int   ri[BM][17];

    const int bx = blockIdx.x;
    const int by = blockIdx.y;
    const int row0 = by * BM;
    const int k0 = bx * KCHUNK;
    const int t = threadIdx.x;
    const int tx = t & 15;
    const int ty = t >> 4;

    float minv[TM];
    int   mini[TM];
#pragma unroll
    for (int i = 0; i < TM; i++) { minv[i] = 3.4e38f; mini[i] = 0; }
    float zrow[TM];
#pragma unroll
    for (int i = 0; i < TM; i++) zrow[i] = zz[row0 + ty * TM + i];
    const int sr = t >> 1;
    const int sdq = (t & 1) * 8;

    for (int kt = 0; kt < KCHUNK / BN; kt++) {
        const int col0 = k0 + kt * BN;
        float acc[TM][TN];
#pragma unroll
        for (int i = 0; i < TM; i++)
#pragma unroll
            for (int j = 0; j < TN; j++) acc[i][j] = 0.f;
        for (int dt = 0; dt < D_DIM; dt += BK) {
            {
                const float* src = z + (size_t)(row0 + sr) * D_DIM + dt + sdq;
                float4 v0 = *(const float4*)(src);
                float4 v1 = *(const float4*)(src + 4);
                As[sdq + 0][sr] = v0.x; As[sdq + 1][sr] = v0.y;
                As[sdq + 2][sr] = v0.z; As[sdq + 3][sr] = v0.w;
                As[sdq + 4][sr] = v1.x; As[sdq + 5][sr] = v1.y;
                As[sdq + 6][sr] = v1.z; As[sdq + 7][sr] = v1.w;
                const float* srcb = cb + (size_t)(col0 + sr) * D_DIM + dt + sdq;
                float4 w0 = *(const float4*)(srcb);
                float4 w1 = *(const float4*)(srcb + 4);
                Bs[sdq + 0][sr] = w0.x; Bs[sdq + 1][sr] = w0.y;
                Bs[sdq + 2][sr] = w0.z; Bs[sdq + 3][sr] = w0.w;
                Bs[sdq + 4][sr] = w1.x; Bs[sdq + 5][sr] = w1.y;
                Bs[sdq + 6][sr] = w1.z; Bs[sdq + 7][sr] = w1.w;
            }
            __syncthreads();
#pragma unroll
            for (int d = 0; d < BK; d++) {
                float a[TM], b[TN];
#pragma unroll
                for (int i = 0; i < TM; i++) a[i] = As[d][ty * TM + i];
#pragma unroll
                for (int j = 0; j < TN; j++) b[j] = Bs[d][tx * TN + j];
#pragma unroll
                for (int i = 0; i < TM; i++)
#pragma unroll
                    for (int j = 0; j < TN; j++)
                        acc[i][j] = fmaf(a[i], b[j], acc[i][j]);
            }
            __syncthreads();
        }
#pragma unroll
        for (int j = 0; j < TN; j++) {
            const int col = col0 + tx * TN + j;
            const float cn = cnorm[col];
#pragma unroll
            for (int i = 0; i < TM; i++) {
                float s1 = fadd_(zrow[i], cn);
                float s = fmaf(-2.f, acc[i][j], s1);
                if (s < minv[i]) { minv[i] = s; mini[i] = col; }
            }
        }
    }
#pragma unroll
    for (int i = 0; i < TM; i++) {
        rv[ty * TM + i][tx] = minv[i];
        ri[ty * TM + i][tx] = mini[i];
    }
    __syncthreads();
    if (t < BM) {
        float bv = rv[t][0];
        int   bi = ri[t][0];
#pragma unroll
        for (int x = 1; x < 16; x++) {
            float v = rv[t][x]; int ii = ri[t][x];
            if (v < bv || (v == bv && ii < bi)) { bv = v; bi = ii; }
        }
        pval[(size_t)(row0 + t) * NCHUNK + bx] = bv;
        pidx[(size_t)(row0 + t) * NCHUNK + bx] = bi;
    }
}

__global__ void finalize_kernel(const float* __restrict__ z,
                                const float* __restrict__ cb,
                                const float* __restrict__ pval,
                                const int* __restrict__ pidx,
                                float* __restrict__ out_zq,
                                float* __restrict__ out_idx,
                                float* __restrict__ rowsum) {
    int row = (blockIdx.x * blockDim.x + threadIdx.x) >> 6;
    int lane = threadIdx.x & 63;
    if (row >= N_ROWS) return;
    float bv = pval[(size_t)row * NCHUNK];
    int   bi = pidx[(size_t)row * NCHUNK];
#pragma unroll
    for (int c = 1; c < NCHUNK; c++) {
        float v = pval[(size_t)row * NCHUNK + c];
        int  ii = pidx[(size_t)row * NCHUNK + c];
        if (v < bv || (v == bv && ii < bi)) { bv = v; bi = ii; }
    }
    const float4* zr = (const float4*)(z + (size_t)row * D_DIM);
    const float4* cr = (const float4*)(cb + (size_t)bi * D_DIM);
    float4* orow = (float4*)(out_zq + (size_t)row * D_DIM);
    float s = 0.f;
#pragma unroll
    for (int i = 0; i < 2; i++) {
        float4 zv = zr[i * 64 + lane];
        float4 cv = cr[i * 64 + lane];
        float4 o;
        o.x = fadd_(zv.x, __fsub_rn(cv.x, zv.x));
        o.y = fadd_(zv.y, __fsub_rn(cv.y, zv.y));
        o.z = fadd_(zv.z, __fsub_rn(cv.z, zv.z));
        o.w = fadd_(zv.w, __fsub_rn(cv.w, zv.w));
        orow[i * 64 + lane] = o;
        float dx = zv.x - cv.x, dy = zv.y - cv.y;
        float dz = zv.z - cv.z, dw = zv.w - cv.w;
        s += dx * dx + dy * dy + dz * dz + dw * dw;
    }
#pragma unroll
    for (int off = 32; off; off >>= 1) s += __shfl_down(s, off, 64);
    if (lane == 0) {
        rowsum[row] = s;
        out_idx[row] = (float)bi;
    }
}

// ---------------------------------------------------------------- launch
extern "C" void kernel_launch(void* const* d_in, const int* in_sizes, int n_in,
                              void* d_out, int out_size, void* d_ws, size_t ws_size,
                              hipStream_t stream) {
    const float* z  = (const float*)d_in[0];
    const float* cb = (const float*)d_in[1];
    float* out      = (float*)d_out;
    float* out_zq   = out;
    float* out_idx  = out + (size_t)N_ROWS * D_DIM;
    float* out_loss = out_idx + N_ROWS;

    float* zz     = (float*)d_ws;                          // 16384 f32
    float* cnorm  = zz + N_ROWS;                           // 4096 f32
    float* rowsum = cnorm + K_CODES;                       // 16384 f32
    u16t*  z_bf   = (u16t*)(rowsum + N_ROWS);              // 16384*512 u16
    u16t*  cb_bf  = z_bf + (size_t)N_ROWS * D_DIM;         // 4096*512 u16
    float* chunkmin = (float*)(cb_bf + (size_t)K_CODES * D_DIM);   // 16384*8 f32
    uint32* cnts  = (uint32*)(chunkmin + (size_t)N_ROWS * NCHUNK); // 16384*8 u32
    uint2* cand   = (uint2*)(cnts + (size_t)N_ROWS * NCHUNK);      // 16384*8*32 uint2
    const size_t WS_NEEDED = (size_t)(N_ROWS + K_CODES + N_ROWS) * 4
                           + (size_t)N_ROWS * D_DIM * 2
                           + (size_t)K_CODES * D_DIM * 2
                           + (size_t)N_ROWS * NCHUNK * 4 * 2
                           + (size_t)N_ROWS * NCHUNK * CCAP * 8;

    if (ws_size >= WS_NEEDED) {
        prep_kernel<<<((N_ROWS + K_CODES) * 4) / 256, 256, 0, stream>>>(
            z, cb, z_bf, cb_bf, zz, cnorm);

        dim3 g1(N_ROWS / 128, NCHUNK);   // x = row-panel (XCD key), y = chunk
        score_gemm_kernel<<<g1, 512, 0, stream>>>(z_bf, cb_bf, cnorm,
                                                  chunkmin, cnts, cand);
        refine_kernel<<<N_ROWS / 4, 256, 0, stream>>>(cand, cnts, chunkmin,
                                                      z, cb, zz, cnorm,
                                                      out_zq, out_idx, rowsum);
        loss_kernel<<<1, 256, 0, stream>>>(rowsum, out_loss);
    } else {
        // fallback: verified round-2 fp32 path (~1 MB ws)
        float* pval = rowsum + N_ROWS;
        int*   pidx = (int*)(pval + (size_t)N_ROWS * NCHUNK);
        rownorm_np_kernel<<<(N_ROWS * 4) / 256, 256, 0, stream>>>(z, N_ROWS, zz);
        rownorm_np_kernel<<<(K_CODES * 4) / 256, 256, 0, stream>>>(cb, K_CODES, cnorm);
        dim3 g2(NCHUNK, N_ROWS / BM);
        vq_argmin_kernel<<<g2, 256, 0, stream>>>(z, cb, zz, cnorm, pval, pidx);
        finalize_kernel<<<N_ROWS / 4, 256, 0, stream>>>(z, cb, pval, pidx,
                                                        out_zq, out_idx, rowsum);
        loss_kernel<<<1, 256, 0, stream>>>(rowsum, out_loss);
    }
}

// Round 10
// 257.484 us; speedup vs baseline: 1.1354x; 1.0179x over previous
//
#include <hip/hip_runtime.h>
#include <math.h>

#define N_ROWS 16384
#define K_CODES 4096
#define D_DIM 512
#define NCHUNK 8
#define KCHUNK (K_CODES / NCHUNK)
#define MARGIN 2.5e-3f
#define CCAP 32   // per-row per-chunk candidate cap (expected ~1-4 used)

typedef unsigned int uint32;
typedef unsigned short u16t;
typedef __attribute__((ext_vector_type(8))) short short8;
typedef __attribute__((ext_vector_type(4))) float f32x4;

__device__ __forceinline__ float fmul_(float a, float b) { return __fmul_rn(a, b); }
__device__ __forceinline__ float fadd_(float a, float b) { return __fadd_rn(a, b); }

// ---------------------------------------------------------------- cvt bf16
__device__ __forceinline__ u16t f2bf(float x) {
    uint32 u = __float_as_uint(x);
    return (u16t)((u + 0x7fffu + ((u >> 16) & 1u)) >> 16);   // RNE
}
// order-preserving float<->uint key for LDS atomicMin on floats (incl. negatives)
__device__ __forceinline__ uint32 fkey(float f) {
    uint32 u = __float_as_uint(f);
    return (u & 0x80000000u) ? ~u : (u | 0x80000000u);
}
__device__ __forceinline__ float fdec(uint32 k) {
    uint32 u = (k & 0x80000000u) ? (k ^ 0x80000000u) : ~k;
    return __uint_as_float(u);
}
// min across each contiguous 16-lane group, pure-VALU DPP (no ds_swizzle).
__device__ __forceinline__ float dpp_min16(float x) {
    int y;
    y = __builtin_amdgcn_update_dpp(0, __float_as_int(x), 0xB1, 0xf, 0xf, true);
    x = fminf(x, __int_as_float(y));
    y = __builtin_amdgcn_update_dpp(0, __float_as_int(x), 0x4E, 0xf, 0xf, true);
    x = fminf(x, __int_as_float(y));
    y = __builtin_amdgcn_update_dpp(0, __float_as_int(x), 0x141, 0xf, 0xf, true);
    x = fminf(x, __int_as_float(y));
    y = __builtin_amdgcn_update_dpp(0, __float_as_int(x), 0x140, 0xf, 0xf, true);
    x = fminf(x, __int_as_float(y));
    return x;
}

// ---------------------------------------------------------------- prep
// FUSED cvt_bf16 + rownorm (verified R7): reads each input once, row-norm
// arithmetic byte-identical to the verified rownorm_np_kernel.
__global__ void prep_kernel(const float* __restrict__ z,
                            const float* __restrict__ cb,
                            u16t* __restrict__ z_bf, u16t* __restrict__ cb_bf,
                            float* __restrict__ zz, float* __restrict__ cnorm) {
    int gid = blockIdx.x * blockDim.x + threadIdx.x;
    int row = gid >> 2;
    int blk = gid & 3;
    const float* src;
    u16t* dst;
    float* outn;
    if (row < N_ROWS) {
        src = z + (size_t)row * D_DIM;
        dst = z_bf + (size_t)row * D_DIM;
        outn = zz + row;
    } else {
        int r = row - N_ROWS;
        if (r >= K_CODES) return;
        src = cb + (size_t)r * D_DIM;
        dst = cb_bf + (size_t)r * D_DIM;
        outn = cnorm + r;
    }
    const float4* p = (const float4*)(src + blk * 128);
    u16t* d = dst + blk * 128;
    float4 v0 = p[0], v1 = p[1];
    {
        short8 o;
        o[0] = (short)f2bf(v0.x); o[1] = (short)f2bf(v0.y);
        o[2] = (short)f2bf(v0.z); o[3] = (short)f2bf(v0.w);
        o[4] = (short)f2bf(v1.x); o[5] = (short)f2bf(v1.y);
        o[6] = (short)f2bf(v1.z); o[7] = (short)f2bf(v1.w);
        *(short8*)d = o;
    }
    float r0 = fmul_(v0.x, v0.x), r1 = fmul_(v0.y, v0.y);
    float r2 = fmul_(v0.z, v0.z), r3 = fmul_(v0.w, v0.w);
    float r4 = fmul_(v1.x, v1.x), r5 = fmul_(v1.y, v1.y);
    float r6 = fmul_(v1.z, v1.z), r7 = fmul_(v1.w, v1.w);
#pragma unroll
    for (int i = 1; i < 16; i++) {
        float4 w0 = p[2 * i], w1 = p[2 * i + 1];
        {
            short8 o;
            o[0] = (short)f2bf(w0.x); o[1] = (short)f2bf(w0.y);
            o[2] = (short)f2bf(w0.z); o[3] = (short)f2bf(w0.w);
            o[4] = (short)f2bf(w1.x); o[5] = (short)f2bf(w1.y);
            o[6] = (short)f2bf(w1.z); o[7] = (short)f2bf(w1.w);
            *(short8*)(d + i * 8) = o;
        }
        r0 = fadd_(r0, fmul_(w0.x, w0.x));
        r1 = fadd_(r1, fmul_(w0.y, w0.y));
        r2 = fadd_(r2, fmul_(w0.z, w0.z));
        r3 = fadd_(r3, fmul_(w0.w, w0.w));
        r4 = fadd_(r4, fmul_(w1.x, w1.x));
        r5 = fadd_(r5, fmul_(w1.y, w1.y));
        r6 = fadd_(r6, fmul_(w1.z, w1.z));
        r7 = fadd_(r7, fmul_(w1.w, w1.w));
    }
    float s = fadd_(fadd_(fadd_(r0, r1), fadd_(r2, r3)),
                    fadd_(fadd_(r4, r5), fadd_(r6, r7)));
    float u = __shfl_down(s, 1, 64);
    float t = fadd_(s, u);
    float w = __shfl_down(t, 2, 64);
    float tot = fadd_(t, w);
    if (blk == 0) *outn = tot;
}

// ---------------------------------------------------------------- rownorm
// (kept for the fallback path; verified R2/R3)
__global__ void rownorm_np_kernel(const float* __restrict__ src, int nrows,
                                  float* __restrict__ out) {
    int gid = blockIdx.x * blockDim.x + threadIdx.x;
    int row = gid >> 2;
    int blk = gid & 3;
    if (row >= nrows) return;
    const float4* p = (const float4*)(src + (size_t)row * D_DIM + blk * 128);
    float4 v0 = p[0], v1 = p[1];
    float r0 = fmul_(v0.x, v0.x), r1 = fmul_(v0.y, v0.y);
    float r2 = fmul_(v0.z, v0.z), r3 = fmul_(v0.w, v0.w);
    float r4 = fmul_(v1.x, v1.x), r5 = fmul_(v1.y, v1.y);
    float r6 = fmul_(v1.z, v1.z), r7 = fmul_(v1.w, v1.w);
#pragma unroll
    for (int i = 1; i < 16; i++) {
        float4 w0 = p[2 * i], w1 = p[2 * i + 1];
        r0 = fadd_(r0, fmul_(w0.x, w0.x));
        r1 = fadd_(r1, fmul_(w0.y, w0.y));
        r2 = fadd_(r2, fmul_(w0.z, w0.z));
        r3 = fadd_(r3, fmul_(w0.w, w0.w));
        r4 = fadd_(r4, fmul_(w1.x, w1.x));
        r5 = fadd_(r5, fmul_(w1.y, w1.y));
        r6 = fadd_(r6, fmul_(w1.z, w1.z));
        r7 = fadd_(r7, fmul_(w1.w, w1.w));
    }
    float s = fadd_(fadd_(fadd_(r0, r1), fadd_(r2, r3)),
                    fadd_(fadd_(r4, r5), fadd_(r6, r7)));
    float u = __shfl_down(s, 1, 64);
    float t = fadd_(s, u);
    float w = __shfl_down(t, 2, 64);
    float tot = fadd_(t, w);
    if (blk == 0) out[row] = tot;
}

// ---------------------------------------------------------------- phase 1
// bf16 MFMA GEMM, fused epilogue. R10: COUNTED-vmcnt 2-DEEP PIPELINE.
// R9 confirmed locality (FETCH 281->82 MB) but MfmaUtil stuck at 24.7%:
// each round still serializes {issue -> __syncthreads vmcnt(0) drain ->
// compute} (~2170 cyc/round vs ~620 compute). R8's __syncthreads dbuf was
// null because the implicit vmcnt(0) drains the prefetch. Escape (m201
// T3/T4, proven plain-HIP): RAW __builtin_amdgcn_s_barrier() + inline-asm
// COUNTED s_waitcnt vmcnt(4) -- slab dt+1's 4 loads stay in flight across
// barriers; never vmcnt(0) in steady state. Schedule per kt:
//   stage(s0->b0); stage(s1->b1);                  // 8 loads outstanding
//   dt: vmcnt(4 | 0 at dt=7); barrier; compute(b[dt&1]); barrier;
//       if dt<6 stage(s_{dt+2} -> b[dt&1]);
// Hazards: RAW by vmcnt+barrier1; WAR re-stage by barrier2; rowminU
// pass2(kt)/pass1(kt+1) by kt+1's dt0 barrier. Math bit-identical.
#define STAGE4(gaP, gbP, bufA, bufB)                                        \
    do {                                                                    \
        __builtin_amdgcn_global_load_lds(                                   \
            (const __attribute__((address_space(1))) void*)(gaP),           \
            (__attribute__((address_space(3))) void*)((char*)(bufA) + w * 1024), 16, 0, 0); \
        __builtin_amdgcn_global_load_lds(                                   \
            (const __attribute__((address_space(1))) void*)((gaP) + 32),    \
            (__attribute__((address_space(3))) void*)((char*)(bufA) + 8192 + w * 1024), 16, 0, 0); \
        __builtin_amdgcn_global_load_lds(                                   \
            (const __attribute__((address_space(1))) void*)(gbP),           \
            (__attribute__((address_space(3))) void*)((char*)(bufB) + w * 1024), 16, 0, 0); \
        __builtin_amdgcn_global_load_lds(                                   \
            (const __attribute__((address_space(1))) void*)((gbP) + 32),    \
            (__attribute__((address_space(3))) void*)((char*)(bufB) + 8192 + w * 1024), 16, 0, 0); \
    } while (0)

__global__ __launch_bounds__(512, 4) void score_gemm_kernel(
    const u16t* __restrict__ zb, const u16t* __restrict__ cbb,
    const float* __restrict__ cnorm,
    float* __restrict__ chunkmin,      // [N_ROWS][NCHUNK]
    uint32* __restrict__ cnts,         // [N_ROWS][NCHUNK]
    uint2* __restrict__ cand) {        // [N_ROWS][NCHUNK][CCAP] {sbits,k}
    __shared__ alignas(16) u16t Ab[2][128 * 64];   // 2 x 16 KB
    __shared__ alignas(16) u16t Bb[2][128 * 64];
    __shared__ uint32 rowminU[128];    // running chunk min (monotone key)
    __shared__ int ccnt[128];          // per-row candidate count (this chunk)

    const int t = threadIdx.x;
    const int panel = blockIdx.x;      // row-panel index (XCD = panel % 8)
    const int chunk = blockIdx.y;      // codebook chunk index
    const int row0 = panel * 128, k0 = chunk * KCHUNK;
    const int w = t >> 6, lane = t & 63;
    const int wx = w & 1, wy = w >> 1;           // wx: col half, wy: row quarter
    const int l15 = lane & 15, quad = lane >> 4;

    if (t < 128) { rowminU[t] = 0xFFFFFFFFu; ccnt[t] = 0; }
    // (ordered before first epilogue use by the dt=0 barrier of kt=0)

    for (int kt = 0; kt < 4; kt++) {
        f32x4 acc[2][4];
#pragma unroll
        for (int i = 0; i < 2; i++)
#pragma unroll
            for (int j = 0; j < 4; j++) acc[i][j] = (f32x4){0.f, 0.f, 0.f, 0.f};

        // per-thread global cursors (wave w stages rows w*16..w*16+15)
        const u16t* ga = zb + (size_t)(row0 + (t >> 2)) * D_DIM + (t & 3) * 8;
        const u16t* gb = cbb + (size_t)(k0 + kt * 128 + (t >> 2)) * D_DIM + (t & 3) * 8;

        // ---- prologue: slabs 0,1 -> buffers 0,1 (8 loads in flight) ----
        STAGE4(ga, gb, Ab[0], Bb[0]);  ga += 64; gb += 64;
        STAGE4(ga, gb, Ab[1], Bb[1]);  ga += 64; gb += 64;

        for (int dt = 0; dt < 8; dt++) {          // 8 x 64-dim slabs
            const int cur = dt & 1;
            // wait for slab dt only; slab dt+1's 4 loads remain in flight
            if (dt < 7) asm volatile("s_waitcnt vmcnt(4)" ::: "memory");
            else        asm volatile("s_waitcnt vmcnt(0)" ::: "memory");
            __builtin_amdgcn_s_barrier();         // slab dt visible to all
            __builtin_amdgcn_sched_barrier(0);
#pragma unroll
            for (int sub = 0; sub < 2; sub++) {
                short8 a[2];
#pragma unroll
                for (int i = 0; i < 2; i++)
                    a[i] = *(const short8*)((char*)Ab[cur] + sub * 8192 +
                                            (wy * 32 + i * 16 + l15) * 64 + quad * 16);
#pragma unroll
                for (int j = 0; j < 4; j++) {
                    short8 b = *(const short8*)((char*)Bb[cur] + sub * 8192 +
                                                (wx * 64 + j * 16 + l15) * 64 + quad * 16);
#pragma unroll
                    for (int i = 0; i < 2; i++)
                        acc[i][j] = __builtin_amdgcn_mfma_f32_16x16x32_bf16(a[i], b, acc[i][j], 0, 0, 0);
                }
            }
            __builtin_amdgcn_s_barrier();         // all waves done reading buf[cur]
            __builtin_amdgcn_sched_barrier(0);
            if (dt < 6) {                         // stage slab dt+2 into buf[cur]
                STAGE4(ga, gb, Ab[cur], Bb[cur]);  ga += 64; gb += 64;
            }
        }

        // ---- fused epilogue ----
        float cnj[4];
#pragma unroll
        for (int j = 0; j < 4; j++)
            cnj[j] = cnorm[k0 + kt * 128 + wx * 64 + j * 16 + l15];

        // pass 1: per-row running min (per-thread j-min + DPP row-min)
#pragma unroll
        for (int i = 0; i < 2; i++) {
#pragma unroll
            for (int r = 0; r < 4; r++) {
                float m = fmaf(-2.f, acc[i][0][r], cnj[0]);
                m = fminf(m, fmaf(-2.f, acc[i][1][r], cnj[1]));
                m = fminf(m, fmaf(-2.f, acc[i][2][r], cnj[2]));
                m = fminf(m, fmaf(-2.f, acc[i][3][r], cnj[3]));
                m = dpp_min16(m);                 // min over the 16 l15 lanes
                if (l15 == 0)
                    atomicMin(&rowminU[wy * 32 + i * 16 + quad * 4 + r], fkey(m));
            }
        }
        __syncthreads();
        // pass 2: append candidates vs running-min threshold (superset-safe;
        // refine re-filters with the exact global min)
#pragma unroll
        for (int i = 0; i < 2; i++) {
#pragma unroll
            for (int r = 0; r < 4; r++) {
                const int rl = wy * 32 + i * 16 + quad * 4 + r;
                const float thr = fdec(rowminU[rl]) + MARGIN;
#pragma unroll
                for (int j = 0; j < 4; j++) {
                    float s = fmaf(-2.f, acc[i][j][r], cnj[j]);
                    if (s <= thr) {
                        int pos = atomicAdd(&ccnt[rl], 1);
                        if (pos < CCAP) {
                            uint2 e;
                            e.x = __float_as_uint(s);
                            e.y = (uint32)(k0 + kt * 128 + wx * 64 + j * 16 + l15);
                            cand[((size_t)(row0 + rl) * NCHUNK + chunk) * CCAP + pos] = e;
                        }
                    }
                }
            }
        }
        // next kt's dt=0 barrier orders pass2 reads of rowminU before the
        // next kt's pass-1 atomicMin updates
    }
    __syncthreads();
    if (t < 128) {
        chunkmin[(size_t)(row0 + t) * NCHUNK + chunk] = fdec(rowminU[t]);
        int c = ccnt[t];
        cnts[(size_t)(row0 + t) * NCHUNK + chunk] = (uint32)(c < CCAP ? c : CCAP);
    }
}

// ---------------------------------------------------------------- phase 2
// ONE WAVE PER ROW, zero barriers, zero LDS (verified R6 structure).
__global__ __launch_bounds__(256) void refine_kernel(
    const uint2* __restrict__ cand, const uint32* __restrict__ cnts,
    const float* __restrict__ chunkmin,
    const float* __restrict__ z, const float* __restrict__ cb,
    const float* __restrict__ zz, const float* __restrict__ cnorm,
    float* __restrict__ out_zq, float* __restrict__ out_idx,
    float* __restrict__ rowsum) {
    const int t = threadIdx.x;
    const int wid = t >> 6, lane = t & 63;
    const int row = blockIdx.x * 4 + wid;

    // global coarse min over the 8 chunk minima (fminf is order-independent)
    float cm = chunkmin[(size_t)row * NCHUNK + (lane & 7)];
    cm = fminf(cm, __shfl_xor(cm, 1, 64));
    cm = fminf(cm, __shfl_xor(cm, 2, 64));
    cm = fminf(cm, __shfl_xor(cm, 4, 64));
    const float thr = cm + MARGIN;

    // z row into regs (verified layout: lane covers elements lane*8..lane*8+7)
    const float* zr = z + (size_t)row * D_DIM;
    float4 z0 = *(const float4*)(zr + lane * 8);
    float4 z1 = *(const float4*)(zr + lane * 8 + 4);
    const float zzr = zz[row];

    float bv = 3.4e38f;
    int bi = 0x7fffffff;
#pragma unroll
    for (int it = 0; it < (NCHUNK * CCAP) / 64; ++it) {
        int idx = it * 64 + lane;
        int c = idx >> 5, s2 = idx & (CCAP - 1);
        uint32 n = cnts[(size_t)row * NCHUNK + c];
        int kk = -1;
        if ((uint32)s2 < n) {
            uint2 e = cand[((size_t)row * NCHUNK + c) * CCAP + s2];
            if (__uint_as_float(e.x) <= thr) kk = (int)e.y;
        }
        unsigned long long mask = __ballot(kk >= 0);
        while (mask) {
            int src = __ffsll((unsigned long long)mask) - 1;
            mask &= (mask - 1);
            int k = __shfl(kk, src, 64);
            // exact np-fp32 dist (verified R3 instruction sequence)
            const float* cr = cb + (size_t)k * D_DIM;
            float4 c0 = *(const float4*)(cr + lane * 8);
            float4 c1 = *(const float4*)(cr + lane * 8 + 4);
            float d = fmul_(z0.x, c0.x);
            d = fmaf(z0.y, c0.y, d); d = fmaf(z0.z, c0.z, d); d = fmaf(z0.w, c0.w, d);
            d = fmaf(z1.x, c1.x, d); d = fmaf(z1.y, c1.y, d);
            d = fmaf(z1.z, c1.z, d); d = fmaf(z1.w, c1.w, d);
#pragma unroll
            for (int off = 1; off < 64; off <<= 1)
                d = fadd_(d, __shfl_xor(d, off, 64));
            float dist = fmaf(-2.f, d, fadd_(zzr, cnorm[k]));
            // (value, index) tie-break; wave-uniform after the full reduce
            if (dist < bv || (dist == bv && k < bi)) { bv = dist; bi = k; }
        }
    }
    // defensive clamp: never let a pathological empty list read OOB
    if (bi == 0x7fffffff) bi = 0;
    if (lane == 0) out_idx[row] = (float)bi;

    // STE + rowsum (verified bit-exact tree via lane-leaf layout)
    const float* cq = cb + (size_t)bi * D_DIM;
    float v[4];
#pragma unroll
    for (int q = 0; q < 4; q++) {
        const int off = q * 128 + lane * 2;
        float2 zv2 = *(const float2*)(zr + off);
        float2 cv2 = *(const float2*)(cq + off);
        float2 o;
        o.x = fadd_(zv2.x, __fsub_rn(cv2.x, zv2.x));
        o.y = fadd_(zv2.y, __fsub_rn(cv2.y, zv2.y));
        *(float2*)(out_zq + (size_t)row * D_DIM + off) = o;
        float dx = zv2.x - cv2.x, dy = zv2.y - cv2.y;
        v[q] = dx * dx + dy * dy;
    }
    float s = fadd_(fadd_(v[0], v[2]), fadd_(v[1], v[3]));
    s = fadd_(s, __shfl_down(s, 32, 64));
    s = fadd_(s, __shfl_down(s, 16, 64));
    s = fadd_(s, __shfl_down(s, 8, 64));
    s = fadd_(s, __shfl_down(s, 4, 64));
    s = fadd_(s, __shfl_down(s, 2, 64));
    s = fadd_(s, __shfl_down(s, 1, 64));
    if (lane == 0) rowsum[row] = s;
}

// ---------------------------------------------------------------- loss
__global__ void loss_kernel(const float* __restrict__ rowsum,
                            float* __restrict__ out_loss) {
    __shared__ float sm[256];
    float s = 0.f;
    for (int i = threadIdx.x; i < N_ROWS; i += 256) s += rowsum[i];
    sm[threadIdx.x] = s;
    __syncthreads();
    for (int st = 128; st; st >>= 1) {
        if (threadIdx.x < st) sm[threadIdx.x] += sm[threadIdx.x + st];
        __syncthreads();
    }
    if (threadIdx.x == 0)
        *out_loss = 1.25f * sm[0] / (float)(N_ROWS * D_DIM);
}

// ================================================================ fallback
// (verified round-2 fp32 path, used only if ws_size too small)
#define BM 128
#define BN 128
#define BK 16
#define TM 8
#define TN 8

__global__ __launch_bounds__(256, 4) void vq_argmin_kernel(
    const float* __restrict__ z, const float* __restrict__ cb,
    const float* __restrict__ zz, const float* __restrict__ cnorm,
    float* __restrict__ pval, int* __restrict__ pidx) {
    __shared__ float As[BK][BM + 4];
    __shared__ float Bs[BK][BN + 4];
    __shared__ float rv[BM][17];
    __shared__ int   ri[BM][17];

    const int bx = blockIdx.x;
    const int by = blockIdx.y;
    const int row0 = by * BM;
    const int k0 = bx * KCHUNK;
    const int t = threadIdx.x;
    const int tx = t & 15;
    const int ty = t >> 4;

    float minv[TM];
    int   mini[TM];
#pragma unroll
    for (int i = 0; i < TM; i++) { minv[i] = 3.4e38f; mini[i] = 0; }
    float zrow[TM];
#pragma unroll
    for (int i = 0; i < TM; i++) zrow[i] = zz[row0 + ty * TM + i];
    const int sr = t >> 1;
    const int sdq = (t & 1) * 8;

    for (int kt = 0; kt < KCHUNK / BN; kt++) {
        const int col0 = k0 + kt * BN;
        float acc[TM][TN];
#pragma unroll
        for (int i = 0; i < TM; i++)
#pragma unroll
            for (int j = 0; j < TN; j++) acc[i][j] = 0.f;
        for (int dt = 0; dt < D_DIM; dt += BK) {
            {
                const float* src = z + (size_t)(row0 + sr) * D_DIM + dt + sdq;
                float4 v0 = *(const float4*)(src);
                float4 v1 = *(const float4*)(src + 4);
                As[sdq + 0][sr] = v0.x; As[sdq + 1][sr] = v0.y;
                As[sdq + 2][sr] = v0.z; As[sdq + 3][sr] = v0.w;
                As[sdq + 4][sr] = v1.x; As[sdq + 5][sr] = v1.y;
                As[sdq + 6][sr] = v1.z; As[sdq + 7][sr] = v1.w;
                const float* srcb = cb + (size_t)(col0 + sr) * D_DIM + dt + sdq;
                float4 w0 = *(const float4*)(srcb);
                float4 w1 = *(const float4*)(srcb + 4);
                Bs[sdq + 0][sr] = w0.x; Bs[sdq + 1][sr] = w0.y;
                Bs[sdq + 2][sr] = w0.z; Bs[sdq + 3][sr] = w0.w;
                Bs[sdq + 4][sr] = w1.x; Bs[sdq + 5][sr] = w1.y;
                Bs[sdq + 6][sr] = w1.z; Bs[sdq + 7][sr] = w1.w;
            }
            __syncthreads();
#pragma unroll
            for (int d = 0; d < BK; d++) {
                float a[TM], b[TN];
#pragma unroll
                for (int i = 0; i < TM; i++) a[i] = As[d][ty * TM + i];
#pragma unroll
                for (int j = 0; j < TN; j++) b[j] = Bs[d][tx * TN + j];
#pragma unroll
                for (int i = 0; i < TM; i++)
#pragma unroll
                    for (int j = 0; j < TN; j++)
                        acc[i][j] = fmaf(a[i], b[j], acc[i][j]);
            }
            __syncthreads();
        }
#pragma unroll
        for (int j = 0; j < TN; j++) {
            const int col = col0 + tx * TN + j;
            const float cn = cnorm[col];
#pragma unroll
            for (int i = 0; i < TM; i++) {
                float s1 = fadd_(zrow[i], cn);
                float s = fmaf(-2.f, acc[i][j], s1);
                if (s < minv[i]) { minv[i] = s; mini[i] = col; }
            }
        }
    }
#pragma unroll
    for (int i = 0; i < TM; i++) {
        rv[ty * TM + i][tx] = minv[i];
        ri[ty * TM + i][tx] = mini[i];
    }
    __syncthreads();
    if (t < BM) {
        float bv = rv[t][0];
        int   bi = ri[t][0];
#pragma unroll
        for (int x = 1; x < 16; x++) {
            float v = rv[t][x]; int ii = ri[t][x];
            if (v < bv || (v == bv && ii < bi)) { bv = v; bi = ii; }
        }
        pval[(size_t)(row0 + t) * NCHUNK + bx] = bv;
        pidx[(size_t)(row0 + t) * NCHUNK + bx] = bi;
    }
}

__global__ void finalize_kernel(const float* __restrict__ z,
                                const float* __restrict__ cb,
                                const float* __restrict__ pval,
                                const int* __restrict__ pidx,
                                float* __restrict__ out_zq,
                                float* __restrict__ out_idx,
                                float* __restrict__ rowsum) {
    int row = (blockIdx.x * blockDim.x + threadIdx.x) >> 6;
    int lane = threadIdx.x & 63;
    if (row >= N_ROWS) return;
    float bv = pval[(size_t)row * NCHUNK];
    int   bi = pidx[(size_t)row * NCHUNK];
#pragma unroll
    for (int c = 1; c < NCHUNK; c++) {
        float v = pval[(size_t)row * NCHUNK + c];
        int  ii = pidx[(size_t)row * NCHUNK + c];
        if (v < bv || (v == bv && ii < bi)) { bv = v; bi = ii; }
    }
    const float4* zr = (const float4*)(z + (size_t)row * D_DIM);
    const float4* cr = (const float4*)(cb + (size_t)bi * D_DIM);
    float4* orow = (float4*)(out_zq + (size_t)row * D_DIM);
    float s = 0.f;
#pragma unroll
    for (int i = 0; i < 2; i++) {
        float4 zv = zr[i * 64 + lane];
        float4 cv = cr[i * 64 + lane];
        float4 o;
        o.x = fadd_(zv.x, __fsub_rn(cv.x, zv.x));
        o.y = fadd_(zv.y, __fsub_rn(cv.y, zv.y));
        o.z = fadd_(zv.z, __fsub_rn(cv.z, zv.z));
        o.w = fadd_(zv.w, __fsub_rn(cv.w, zv.w));
        orow[i * 64 + lane] = o;
        float dx = zv.x - cv.x, dy = zv.y - cv.y;
        float dz = zv.z - cv.z, dw = zv.w - cv.w;
        s += dx * dx + dy * dy + dz * dz + dw * dw;
    }
#pragma unroll
    for (int off = 32; off; off >>= 1) s += __shfl_down(s, off, 64);
    if (lane == 0) {
        rowsum[row] = s;
        out_idx[row] = (float)bi;
    }
}

// ---------------------------------------------------------------- launch
extern "C" void kernel_launch(void* const* d_in, const int* in_sizes, int n_in,
                              void* d_out, int out_size, void* d_ws, size_t ws_size,
                              hipStream_t stream) {
    const float* z  = (const float*)d_in[0];
    const float* cb = (const float*)d_in[1];
    float* out      = (float*)d_out;
    float* out_zq   = out;
    float* out_idx  = out + (size_t)N_ROWS * D_DIM;
    float* out_loss = out_idx + N_ROWS;

    float* zz     = (float*)d_ws;                          // 16384 f32
    float* cnorm  = zz + N_ROWS;                           // 4096 f32
    float* rowsum = cnorm + K_CODES;                       // 16384 f32
    u16t*  z_bf   = (u16t*)(rowsum + N_ROWS);              // 16384*512 u16
    u16t*  cb_bf  = z_bf + (size_t)N_ROWS * D_DIM;         // 4096*512 u16
    float* chunkmin = (float*)(cb_bf + (size_t)K_CODES * D_DIM);   // 16384*8 f32
    uint32* cnts  = (uint32*)(chunkmin + (size_t)N_ROWS * NCHUNK); // 16384*8 u32
    uint2* cand   = (uint2*)(cnts + (size_t)N_ROWS * NCHUNK);      // 16384*8*32 uint2
    const size_t WS_NEEDED = (size_t)(N_ROWS + K_CODES + N_ROWS) * 4
                           + (size_t)N_ROWS * D_DIM * 2
                           + (size_t)K_CODES * D_DIM * 2
                           + (size_t)N_ROWS * NCHUNK * 4 * 2
                           + (size_t)N_ROWS * NCHUNK * CCAP * 8;

    if (ws_size >= WS_NEEDED) {
        prep_kernel<<<((N_ROWS + K_CODES) * 4) / 256, 256, 0, stream>>>(
            z, cb, z_bf, cb_bf, zz, cnorm);

        dim3 g1(N_ROWS / 128, NCHUNK);   // x = row-panel (XCD key), y = chunk
        score_gemm_kernel<<<g1, 512, 0, stream>>>(z_bf, cb_bf, cnorm,
                                                  chunkmin, cnts, cand);
        refine_kernel<<<N_ROWS / 4, 256, 0, stream>>>(cand, cnts, chunkmin,
                                                      z, cb, zz, cnorm,
                                                      out_zq, out_idx, rowsum);
        loss_kernel<<<1, 256, 0, stream>>>(rowsum, out_loss);
    } else {
        // fallback: verified round-2 fp32 path (~1 MB ws)
        float* pval = rowsum + N_ROWS;
        int*   pidx = (int*)(pval + (size_t)N_ROWS * NCHUNK);
        rownorm_np_kernel<<<(N_ROWS * 4) / 256, 256, 0, stream>>>(z, N_ROWS, zz);
        rownorm_np_kernel<<<(K_CODES * 4) / 256, 256, 0, stream>>>(cb, K_CODES, cnorm);
        dim3 g2(NCHUNK, N_ROWS / BM);
        vq_argmin_kernel<<<g2, 256, 0, stream>>>(z, cb, zz, cnorm, pval, pidx);
        finalize_kernel<<<N_ROWS / 4, 256, 0, stream>>>(z, cb, pval, pidx,
                                                        out_zq, out_idx, rowsum);
        loss_kernel<<<1, 256, 0, stream>>>(rowsum, out_loss);
    }
}

// Round 11
// 255.323 us; speedup vs baseline: 1.1450x; 1.0085x over previous
//
#include <hip/hip_runtime.h>
#include <math.h>

#define N_ROWS 16384
#define K_CODES 4096
#define D_DIM 512
#define NCHUNK 8
#define KCHUNK (K_CODES / NCHUNK)
#define MARGIN 2.5e-3f
#define CCAP 32   // per-row per-chunk candidate cap (expected ~1-4 used)

typedef unsigned int uint32;
typedef unsigned short u16t;
typedef __attribute__((ext_vector_type(8))) short short8;
typedef __attribute__((ext_vector_type(4))) float f32x4;

__device__ __forceinline__ float fmul_(float a, float b) { return __fmul_rn(a, b); }
__device__ __forceinline__ float fadd_(float a, float b) { return __fadd_rn(a, b); }

// ---------------------------------------------------------------- cvt bf16
__device__ __forceinline__ u16t f2bf(float x) {
    uint32 u = __float_as_uint(x);
    return (u16t)((u + 0x7fffu + ((u >> 16) & 1u)) >> 16);   // RNE
}
// order-preserving float<->uint key for LDS atomicMin on floats (incl. negatives)
__device__ __forceinline__ uint32 fkey(float f) {
    uint32 u = __float_as_uint(f);
    return (u & 0x80000000u) ? ~u : (u | 0x80000000u);
}
__device__ __forceinline__ float fdec(uint32 k) {
    uint32 u = (k & 0x80000000u) ? (k ^ 0x80000000u) : ~k;
    return __uint_as_float(u);
}
// min across each contiguous 16-lane group, pure-VALU DPP (no ds_swizzle).
__device__ __forceinline__ float dpp_min16(float x) {
    int y;
    y = __builtin_amdgcn_update_dpp(0, __float_as_int(x), 0xB1, 0xf, 0xf, true);
    x = fminf(x, __int_as_float(y));
    y = __builtin_amdgcn_update_dpp(0, __float_as_int(x), 0x4E, 0xf, 0xf, true);
    x = fminf(x, __int_as_float(y));
    y = __builtin_amdgcn_update_dpp(0, __float_as_int(x), 0x141, 0xf, 0xf, true);
    x = fminf(x, __int_as_float(y));
    y = __builtin_amdgcn_update_dpp(0, __float_as_int(x), 0x140, 0xf, 0xf, true);
    x = fminf(x, __int_as_float(y));
    return x;
}

// ---------------------------------------------------------------- prep
// FUSED cvt_bf16 + rownorm (verified R7): reads each input once, row-norm
// arithmetic byte-identical to the verified rownorm_np_kernel.
__global__ void prep_kernel(const float* __restrict__ z,
                            const float* __restrict__ cb,
                            u16t* __restrict__ z_bf, u16t* __restrict__ cb_bf,
                            float* __restrict__ zz, float* __restrict__ cnorm) {
    int gid = blockIdx.x * blockDim.x + threadIdx.x;
    int row = gid >> 2;
    int blk = gid & 3;
    const float* src;
    u16t* dst;
    float* outn;
    if (row < N_ROWS) {
        src = z + (size_t)row * D_DIM;
        dst = z_bf + (size_t)row * D_DIM;
        outn = zz + row;
    } else {
        int r = row - N_ROWS;
        if (r >= K_CODES) return;
        src = cb + (size_t)r * D_DIM;
        dst = cb_bf + (size_t)r * D_DIM;
        outn = cnorm + r;
    }
    const float4* p = (const float4*)(src + blk * 128);
    u16t* d = dst + blk * 128;
    float4 v0 = p[0], v1 = p[1];
    {
        short8 o;
        o[0] = (short)f2bf(v0.x); o[1] = (short)f2bf(v0.y);
        o[2] = (short)f2bf(v0.z); o[3] = (short)f2bf(v0.w);
        o[4] = (short)f2bf(v1.x); o[5] = (short)f2bf(v1.y);
        o[6] = (short)f2bf(v1.z); o[7] = (short)f2bf(v1.w);
        *(short8*)d = o;
    }
    float r0 = fmul_(v0.x, v0.x), r1 = fmul_(v0.y, v0.y);
    float r2 = fmul_(v0.z, v0.z), r3 = fmul_(v0.w, v0.w);
    float r4 = fmul_(v1.x, v1.x), r5 = fmul_(v1.y, v1.y);
    float r6 = fmul_(v1.z, v1.z), r7 = fmul_(v1.w, v1.w);
#pragma unroll
    for (int i = 1; i < 16; i++) {
        float4 w0 = p[2 * i], w1 = p[2 * i + 1];
        {
            short8 o;
            o[0] = (short)f2bf(w0.x); o[1] = (short)f2bf(w0.y);
            o[2] = (short)f2bf(w0.z); o[3] = (short)f2bf(w0.w);
            o[4] = (short)f2bf(w1.x); o[5] = (short)f2bf(w1.y);
            o[6] = (short)f2bf(w1.z); o[7] = (short)f2bf(w1.w);
            *(short8*)(d + i * 8) = o;
        }
        r0 = fadd_(r0, fmul_(w0.x, w0.x));
        r1 = fadd_(r1, fmul_(w0.y, w0.y));
        r2 = fadd_(r2, fmul_(w0.z, w0.z));
        r3 = fadd_(r3, fmul_(w0.w, w0.w));
        r4 = fadd_(r4, fmul_(w1.x, w1.x));
        r5 = fadd_(r5, fmul_(w1.y, w1.y));
        r6 = fadd_(r6, fmul_(w1.z, w1.z));
        r7 = fadd_(r7, fmul_(w1.w, w1.w));
    }
    float s = fadd_(fadd_(fadd_(r0, r1), fadd_(r2, r3)),
                    fadd_(fadd_(r4, r5), fadd_(r6, r7)));
    float u = __shfl_down(s, 1, 64);
    float t = fadd_(s, u);
    float w = __shfl_down(t, 2, 64);
    float tot = fadd_(t, w);
    if (blk == 0) *outn = tot;
}

// ---------------------------------------------------------------- rownorm
// (kept for the fallback path; verified R2/R3)
__global__ void rownorm_np_kernel(const float* __restrict__ src, int nrows,
                                  float* __restrict__ out) {
    int gid = blockIdx.x * blockDim.x + threadIdx.x;
    int row = gid >> 2;
    int blk = gid & 3;
    if (row >= nrows) return;
    const float4* p = (const float4*)(src + (size_t)row * D_DIM + blk * 128);
    float4 v0 = p[0], v1 = p[1];
    float r0 = fmul_(v0.x, v0.x), r1 = fmul_(v0.y, v0.y);
    float r2 = fmul_(v0.z, v0.z), r3 = fmul_(v0.w, v0.w);
    float r4 = fmul_(v1.x, v1.x), r5 = fmul_(v1.y, v1.y);
    float r6 = fmul_(v1.z, v1.z), r7 = fmul_(v1.w, v1.w);
#pragma unroll
    for (int i = 1; i < 16; i++) {
        float4 w0 = p[2 * i], w1 = p[2 * i + 1];
        r0 = fadd_(r0, fmul_(w0.x, w0.x));
        r1 = fadd_(r1, fmul_(w0.y, w0.y));
        r2 = fadd_(r2, fmul_(w0.z, w0.z));
        r3 = fadd_(r3, fmul_(w0.w, w0.w));
        r4 = fadd_(r4, fmul_(w1.x, w1.x));
        r5 = fadd_(r5, fmul_(w1.y, w1.y));
        r6 = fadd_(r6, fmul_(w1.z, w1.z));
        r7 = fadd_(r7, fmul_(w1.w, w1.w));
    }
    float s = fadd_(fadd_(fadd_(r0, r1), fadd_(r2, r3)),
                    fadd_(fadd_(r4, r5), fadd_(r6, r7)));
    float u = __shfl_down(s, 1, 64);
    float t = fadd_(s, u);
    float w = __shfl_down(t, 2, 64);
    float tot = fadd_(t, w);
    if (blk == 0) out[row] = tot;
}

// ---------------------------------------------------------------- phase 1
// bf16 MFMA GEMM, fused epilogue. R11: R9 base (best gemm, single-buffer
// BK=64, XCD-transposed grid) + T2 LDS SWIZZLE. R10 post-mortem: kernel is
// LDS-bank-conflict-bound -- fragment read (row*64 + quad*16) puts 16
// same-quad lanes (row stride 64 B = 16 banks) on 2 bank-starts = 8-way
// conflict (~2.94x, m136); round time 2.2K cyc == conflicted-LDS estimate;
// SQ_LDS_BANK_CONFLICT 12.66M constant through R7-R10.
// Fix (rule #21, both-sides-or-neither with global_load_lds):
//   write side: LDS stays LINEAR (lane x 16B); the 16B-slot permutation is
//     applied by PRE-SWIZZLING the global source column: lane fetches
//     k-group qg = ((t&3) - ((t>>3)&3)) & 3 instead of (t&3).
//     => LDS (row r, slot s) holds k-group (s - (r>>1)) & 3.
//   read side: slot = (quad + (l15>>1)) & 3 => retrieves exactly k-group
//     quad of row r. Fragment semantics bit-identical; lanes 0-15 now hit
//     8 distinct bank-starts x 2 lanes = 2-way (free).
__global__ __launch_bounds__(512, 4) void score_gemm_kernel(
    const u16t* __restrict__ zb, const u16t* __restrict__ cbb,
    const float* __restrict__ cnorm,
    float* __restrict__ chunkmin,      // [N_ROWS][NCHUNK]
    uint32* __restrict__ cnts,         // [N_ROWS][NCHUNK]
    uint2* __restrict__ cand) {        // [N_ROWS][NCHUNK][CCAP] {sbits,k}
    __shared__ alignas(16) u16t Ab[128 * 64];   // [2][128][32] bf16, 16 KB
    __shared__ alignas(16) u16t Bb[128 * 64];
    __shared__ uint32 rowminU[128];    // running chunk min (monotone key)
    __shared__ int ccnt[128];          // per-row candidate count (this chunk)

    const int t = threadIdx.x;
    const int panel = blockIdx.x;      // row-panel index (XCD = panel % 8)
    const int chunk = blockIdx.y;      // codebook chunk index
    const int row0 = panel * 128, k0 = chunk * KCHUNK;
    const int w = t >> 6, lane = t & 63;
    const int wx = w & 1, wy = w >> 1;           // wx: col half, wy: row quarter
    const int l15 = lane & 15, quad = lane >> 4;
    // T2 swizzle terms (see header comment)
    const int qg = ((t & 3) - ((t >> 3) & 3)) & 3;      // staging source slot
    const int sl16 = (((quad + (l15 >> 1)) & 3) << 4);  // read slot byte offset

    if (t < 128) { rowminU[t] = 0xFFFFFFFFu; ccnt[t] = 0; }
    // (ordered before first use by the dt-loop's leading __syncthreads)

    for (int kt = 0; kt < 4; kt++) {
        f32x4 acc[2][4];
#pragma unroll
        for (int i = 0; i < 2; i++)
#pragma unroll
            for (int j = 0; j < 4; j++) acc[i][j] = (f32x4){0.f, 0.f, 0.f, 0.f};

        // per-thread global cursors (wave w stages rows w*16..w*16+15);
        // column = qg*8 (pre-swizzled source; linear LDS dest)
        const u16t* ga = zb + (size_t)(row0 + (t >> 2)) * D_DIM + qg * 8;
        const u16t* gb = cbb + (size_t)(k0 + kt * 128 + (t >> 2)) * D_DIM + qg * 8;

        for (int dt = 0; dt < 8; dt++) {          // 8 x 64-dim slabs
            __syncthreads();
            // sub0 (dims +0..31) and sub1 (dims +32..63) of both operands
            __builtin_amdgcn_global_load_lds(
                (const __attribute__((address_space(1))) void*)ga,
                (__attribute__((address_space(3))) void*)((char*)Ab + w * 1024),
                16, 0, 0);
            __builtin_amdgcn_global_load_lds(
                (const __attribute__((address_space(1))) void*)(ga + 32),
                (__attribute__((address_space(3))) void*)((char*)Ab + 8192 + w * 1024),
                16, 0, 0);
            __builtin_amdgcn_global_load_lds(
                (const __attribute__((address_space(1))) void*)gb,
                (__attribute__((address_space(3))) void*)((char*)Bb + w * 1024),
                16, 0, 0);
            __builtin_amdgcn_global_load_lds(
                (const __attribute__((address_space(1))) void*)(gb + 32),
                (__attribute__((address_space(3))) void*)((char*)Bb + 8192 + w * 1024),
                16, 0, 0);
            ga += 64; gb += 64;
            __syncthreads();
#pragma unroll
            for (int sub = 0; sub < 2; sub++) {
                short8 a[2];
#pragma unroll
                for (int i = 0; i < 2; i++)
                    a[i] = *(const short8*)((char*)Ab + sub * 8192 +
                                            (wy * 32 + i * 16 + l15) * 64 + sl16);
#pragma unroll
                for (int j = 0; j < 4; j++) {
                    short8 b = *(const short8*)((char*)Bb + sub * 8192 +
                                                (wx * 64 + j * 16 + l15) * 64 + sl16);
#pragma unroll
                    for (int i = 0; i < 2; i++)
                        acc[i][j] = __builtin_amdgcn_mfma_f32_16x16x32_bf16(a[i], b, acc[i][j], 0, 0, 0);
                }
            }
        }

        // ---- fused epilogue ----
        float cnj[4];
#pragma unroll
        for (int j = 0; j < 4; j++)
            cnj[j] = cnorm[k0 + kt * 128 + wx * 64 + j * 16 + l15];

        // pass 1: per-row running min (per-thread j-min + DPP row-min)
#pragma unroll
        for (int i = 0; i < 2; i++) {
#pragma unroll
            for (int r = 0; r < 4; r++) {
                float m = fmaf(-2.f, acc[i][0][r], cnj[0]);
                m = fminf(m, fmaf(-2.f, acc[i][1][r], cnj[1]));
                m = fminf(m, fmaf(-2.f, acc[i][2][r], cnj[2]));
                m = fminf(m, fmaf(-2.f, acc[i][3][r], cnj[3]));
                m = dpp_min16(m);                 // min over the 16 l15 lanes
                if (l15 == 0)
                    atomicMin(&rowminU[wy * 32 + i * 16 + quad * 4 + r], fkey(m));
            }
        }
        __syncthreads();
        // pass 2: append candidates vs running-min threshold (superset-safe;
        // refine re-filters with the exact global min)
#pragma unroll
        for (int i = 0; i < 2; i++) {
#pragma unroll
            for (int r = 0; r < 4; r++) {
                const int rl = wy * 32 + i * 16 + quad * 4 + r;
                const float thr = fdec(rowminU[rl]) + MARGIN;
#pragma unroll
                for (int j = 0; j < 4; j++) {
                    float s = fmaf(-2.f, acc[i][j][r], cnj[j]);
                    if (s <= thr) {
                        int pos = atomicAdd(&ccnt[rl], 1);
                        if (pos < CCAP) {
                            uint2 e;
                            e.x = __float_as_uint(s);
                            e.y = (uint32)(k0 + kt * 128 + wx * 64 + j * 16 + l15);
                            cand[((size_t)(row0 + rl) * NCHUNK + chunk) * CCAP + pos] = e;
                        }
                    }
                }
            }
        }
        // next kt's dt-loop leading __syncthreads orders pass2 reads of
        // rowminU before the next kt's atomicMin updates
    }
    __syncthreads();
    if (t < 128) {
        chunkmin[(size_t)(row0 + t) * NCHUNK + chunk] = fdec(rowminU[t]);
        int c = ccnt[t];
        cnts[(size_t)(row0 + t) * NCHUNK + chunk] = (uint32)(c < CCAP ? c : CCAP);
    }
}

// ---------------------------------------------------------------- phase 2
// ONE WAVE PER ROW, zero barriers, zero LDS (verified R6 structure).
__global__ __launch_bounds__(256) void refine_kernel(
    const uint2* __restrict__ cand, const uint32* __restrict__ cnts,
    const float* __restrict__ chunkmin,
    const float* __restrict__ z, const float* __restrict__ cb,
    const float* __restrict__ zz, const float* __restrict__ cnorm,
    float* __restrict__ out_zq, float* __restrict__ out_idx,
    float* __restrict__ rowsum) {
    const int t = threadIdx.x;
    const int wid = t >> 6, lane = t & 63;
    const int row = blockIdx.x * 4 + wid;

    // global coarse min over the 8 chunk minima (fminf is order-independent)
    float cm = chunkmin[(size_t)row * NCHUNK + (lane & 7)];
    cm = fminf(cm, __shfl_xor(cm, 1, 64));
    cm = fminf(cm, __shfl_xor(cm, 2, 64));
    cm = fminf(cm, __shfl_xor(cm, 4, 64));
    const float thr = cm + MARGIN;

    // z row into regs (verified layout: lane covers elements lane*8..lane*8+7)
    const float* zr = z + (size_t)row * D_DIM;
    float4 z0 = *(const float4*)(zr + lane * 8);
    float4 z1 = *(const float4*)(zr + lane * 8 + 4);
    const float zzr = zz[row];

    float bv = 3.4e38f;
    int bi = 0x7fffffff;
#pragma unroll
    for (int it = 0; it < (NCHUNK * CCAP) / 64; ++it) {
        int idx = it * 64 + lane;
        int c = idx >> 5, s2 = idx & (CCAP - 1);
        uint32 n = cnts[(size_t)row * NCHUNK + c];
        int kk = -1;
        if ((uint32)s2 < n) {
            uint2 e = cand[((size_t)row * NCHUNK + c) * CCAP + s2];
            if (__uint_as_float(e.x) <= thr) kk = (int)e.y;
        }
        unsigned long long mask = __ballot(kk >= 0);
        while (mask) {
            int src = __ffsll((unsigned long long)mask) - 1;
            mask &= (mask - 1);
            int k = __shfl(kk, src, 64);
            // exact np-fp32 dist (verified R3 instruction sequence)
            const float* cr = cb + (size_t)k * D_DIM;
            float4 c0 = *(const float4*)(cr + lane * 8);
            float4 c1 = *(const float4*)(cr + lane * 8 + 4);
            float d = fmul_(z0.x, c0.x);
            d = fmaf(z0.y, c0.y, d); d = fmaf(z0.z, c0.z, d); d = fmaf(z0.w, c0.w, d);
            d = fmaf(z1.x, c1.x, d); d = fmaf(z1.y, c1.y, d);
            d = fmaf(z1.z, c1.z, d); d = fmaf(z1.w, c1.w, d);
#pragma unroll
            for (int off = 1; off < 64; off <<= 1)
                d = fadd_(d, __shfl_xor(d, off, 64));
            float dist = fmaf(-2.f, d, fadd_(zzr, cnorm[k]));
            // (value, index) tie-break; wave-uniform after the full reduce
            if (dist < bv || (dist == bv && k < bi)) { bv = dist; bi = k; }
        }
    }
    // defensive clamp: never let a pathological empty list read OOB
    if (bi == 0x7fffffff) bi = 0;
    if (lane == 0) out_idx[row] = (float)bi;

    // STE + rowsum (verified bit-exact tree via lane-leaf layout)
    const float* cq = cb + (size_t)bi * D_DIM;
    float v[4];
#pragma unroll
    for (int q = 0; q < 4; q++) {
        const int off = q * 128 + lane * 2;
        float2 zv2 = *(const float2*)(zr + off);
        float2 cv2 = *(const float2*)(cq + off);
        float2 o;
        o.x = fadd_(zv2.x, __fsub_rn(cv2.x, zv2.x));
        o.y = fadd_(zv2.y, __fsub_rn(cv2.y, zv2.y));
        *(float2*)(out_zq + (size_t)row * D_DIM + off) = o;
        float dx = zv2.x - cv2.x, dy = zv2.y - cv2.y;
        v[q] = dx * dx + dy * dy;
    }
    float s = fadd_(fadd_(v[0], v[2]), fadd_(v[1], v[3]));
    s = fadd_(s, __shfl_down(s, 32, 64));
    s = fadd_(s, __shfl_down(s, 16, 64));
    s = fadd_(s, __shfl_down(s, 8, 64));
    s = fadd_(s, __shfl_down(s, 4, 64));
    s = fadd_(s, __shfl_down(s, 2, 64));
    s = fadd_(s, __shfl_down(s, 1, 64));
    if (lane == 0) rowsum[row] = s;
}

// ---------------------------------------------------------------- loss
__global__ void loss_kernel(const float* __restrict__ rowsum,
                            float* __restrict__ out_loss) {
    __shared__ float sm[256];
    float s = 0.f;
    for (int i = threadIdx.x; i < N_ROWS; i += 256) s += rowsum[i];
    sm[threadIdx.x] = s;
    __syncthreads();
    for (int st = 128; st; st >>= 1) {
        if (threadIdx.x < st) sm[threadIdx.x] += sm[threadIdx.x + st];
        __syncthreads();
    }
    if (threadIdx.x == 0)
        *out_loss = 1.25f * sm[0] / (float)(N_ROWS * D_DIM);
}

// ================================================================ fallback
// (verified round-2 fp32 path, used only if ws_size too small)
#define BM 128
#define BN 128
#define BK 16
#define TM 8
#define TN 8

__global__ __launch_bounds__(256, 4) void vq_argmin_kernel(
    const float* __restrict__ z, const float* __restrict__ cb,
    const float* __restrict__ zz, const float* __restrict__ cnorm,
    float* __restrict__ pval, int* __restrict__ pidx) {
    __shared__ float As[BK][BM + 4];
    __shared__ float Bs[BK][BN + 4];
    __shared__ float rv[BM][17];
    __shared__ int   ri[BM][17];

    const int bx = blockIdx.x;
    const int by = blockIdx.y;
    const int row0 = by * BM;
    const int k0 = bx * KCHUNK;
    const int t = threadIdx.x;
    const int tx = t & 15;
    const int ty = t >> 4;

    float minv[TM];
    int   mini[TM];
#pragma unroll
    for (int i = 0; i < TM; i++) { minv[i] = 3.4e38f; mini[i] = 0; }
    float zrow[TM];
#pragma unroll
    for (int i = 0; i < TM; i++) zrow[i] = zz[row0 + ty * TM + i];
    const int sr = t >> 1;
    const int sdq = (t & 1) * 8;

    for (int kt = 0; kt < KCHUNK / BN; kt++) {
        const int col0 = k0 + kt * BN;
        float acc[TM][TN];
#pragma unroll
        for (int i = 0; i < TM; i++)
#pragma unroll
            for (int j = 0; j < TN; j++) acc[i][j] = 0.f;
        for (int dt = 0; dt < D_DIM; dt += BK) {
            {
                const float* src = z + (size_t)(row0 + sr) * D_DIM + dt + sdq;
                float4 v0 = *(const float4*)(src);
                float4 v1 = *(const float4*)(src + 4);
                As[sdq + 0][sr] = v0.x; As[sdq + 1][sr] = v0.y;
                As[sdq + 2][sr] = v0.z; As[sdq + 3][sr] = v0.w;
                As[sdq + 4][sr] = v1.x; As[sdq + 5][sr] = v1.y;
                As[sdq + 6][sr] = v1.z; As[sdq + 7][sr] = v1.w;
                const float* srcb = cb + (size_t)(col0 + sr) * D_DIM + dt + sdq;
                float4 w0 = *(const float4*)(srcb);
                float4 w1 = *(const float4*)(srcb + 4);
                Bs[sdq + 0][sr] = w0.x; Bs[sdq + 1][sr] = w0.y;
                Bs[sdq + 2][sr] = w0.z; Bs[sdq + 3][sr] = w0.w;
                Bs[sdq + 4][sr] = w1.x; Bs[sdq + 5][sr] = w1.y;
                Bs[sdq + 6][sr] = w1.z; Bs[sdq + 7][sr] = w1.w;
            }
            __syncthreads();
#pragma unroll
            for (int d = 0; d < BK; d++) {
                float a[TM], b[TN];
#pragma unroll
                for (int i = 0; i < TM; i++) a[i] = As[d][ty * TM + i];
#pragma unroll
                for (int j = 0; j < TN; j++) b[j] = Bs[d][tx * TN + j];
#pragma unroll
                for (int i = 0; i < TM; i++)
#pragma unroll
                    for (int j = 0; j < TN; j++)
                        acc[i][j] = fmaf(a[i], b[j], acc[i][j]);
            }
            __syncthreads();
        }
#pragma unroll
        for (int j = 0; j < TN; j++) {
            const int col = col0 + tx * TN + j;
            const float cn = cnorm[col];
#pragma unroll
            for (int i = 0; i < TM; i++) {
                float s1 = fadd_(zrow[i], cn);
                float s = fmaf(-2.f, acc[i][j], s1);
                if (s < minv[i]) { minv[i] = s; mini[i] = col; }
            }
        }
    }
#pragma unroll
    for (int i = 0; i < TM; i++) {
        rv[ty * TM + i][tx] = minv[i];
        ri[ty * TM + i][tx] = mini[i];
    }
    __syncthreads();
    if (t < BM) {
        float bv = rv[t][0];
        int   bi = ri[t][0];
#pragma unroll
        for (int x = 1; x < 16; x++) {
            float v = rv[t][x]; int ii = ri[t][x];
            if (v < bv || (v == bv && ii < bi)) { bv = v; bi = ii; }
        }
        pval[(size_t)(row0 + t) * NCHUNK + bx] = bv;
        pidx[(size_t)(row0 + t) * NCHUNK + bx] = bi;
    }
}

__global__ void finalize_kernel(const float* __restrict__ z,
                                const float* __restrict__ cb,
                                const float* __restrict__ pval,
                                const int* __restrict__ pidx,
                                float* __restrict__ out_zq,
                                float* __restrict__ out_idx,
                                float* __restrict__ rowsum) {
    int row = (blockIdx.x * blockDim.x + threadIdx.x) >> 6;
    int lane = threadIdx.x & 63;
    if (row >= N_ROWS) return;
    float bv = pval[(size_t)row * NCHUNK];
    int   bi = pidx[(size_t)row * NCHUNK];
#pragma unroll
    for (int c = 1; c < NCHUNK; c++) {
        float v = pval[(size_t)row * NCHUNK + c];
        int  ii = pidx[(size_t)row * NCHUNK + c];
        if (v < bv || (v == bv && ii < bi)) { bv = v; bi = ii; }
    }
    const float4* zr = (const float4*)(z + (size_t)row * D_DIM);
    const float4* cr = (const float4*)(cb + (size_t)bi * D_DIM);
    float4* orow = (float4*)(out_zq + (size_t)row * D_DIM);
    float s = 0.f;
#pragma unroll
    for (int i = 0; i < 2; i++) {
        float4 zv = zr[i * 64 + lane];
        float4 cv = cr[i * 64 + lane];
        float4 o;
        o.x = fadd_(zv.x, __fsub_rn(cv.x, zv.x));
        o.y = fadd_(zv.y, __fsub_rn(cv.y, zv.y));
        o.z = fadd_(zv.z, __fsub_rn(cv.z, zv.z));
        o.w = fadd_(zv.w, __fsub_rn(cv.w, zv.w));
        orow[i * 64 + lane] = o;
        float dx = zv.x - cv.x, dy = zv.y - cv.y;
        float dz = zv.z - cv.z, dw = zv.w - cv.w;
        s += dx * dx + dy * dy + dz * dz + dw * dw;
    }
#pragma unroll
    for (int off = 32; off; off >>= 1) s += __shfl_down(s, off, 64);
    if (lane == 0) {
        rowsum[row] = s;
        out_idx[row] = (float)bi;
    }
}

// ---------------------------------------------------------------- launch
extern "C" void kernel_launch(void* const* d_in, const int* in_sizes, int n_in,
                              void* d_out, int out_size, void* d_ws, size_t ws_size,
                              hipStream_t stream) {
    const float* z  = (const float*)d_in[0];
    const float* cb = (const float*)d_in[1];
    float* out      = (float*)d_out;
    float* out_zq   = out;
    float* out_idx  = out + (size_t)N_ROWS * D_DIM;
    float* out_loss = out_idx + N_ROWS;

    float* zz     = (float*)d_ws;                          // 16384 f32
    float* cnorm  = zz + N_ROWS;                           // 4096 f32
    float* rowsum = cnorm + K_CODES;                       // 16384 f32
    u16t*  z_bf   = (u16t*)(rowsum + N_ROWS);              // 16384*512 u16
    u16t*  cb_bf  = z_bf + (size_t)N_ROWS * D_DIM;         // 4096*512 u16
    float* chunkmin = (float*)(cb_bf + (size_t)K_CODES * D_DIM);   // 16384*8 f32
    uint32* cnts  = (uint32*)(chunkmin + (size_t)N_ROWS * NCHUNK); // 16384*8 u32
    uint2* cand   = (uint2*)(cnts + (size_t)N_ROWS * NCHUNK);      // 16384*8*32 uint2
    const size_t WS_NEEDED = (size_t)(N_ROWS + K_CODES + N_ROWS) * 4
                           + (size_t)N_ROWS * D_DIM * 2
                           + (size_t)K_CODES * D_DIM * 2
                           + (size_t)N_ROWS * NCHUNK * 4 * 2
                           + (size_t)N_ROWS * NCHUNK * CCAP * 8;

    if (ws_size >= WS_NEEDED) {
        prep_kernel<<<((N_ROWS + K_CODES) * 4) / 256, 256, 0, stream>>>(
            z, cb, z_bf, cb_bf, zz, cnorm);

        dim3 g1(N_ROWS / 128, NCHUNK);   // x = row-panel (XCD key), y = chunk
        score_gemm_kernel<<<g1, 512, 0, stream>>>(z_bf, cb_bf, cnorm,
                                                  chunkmin, cnts, cand);
        refine_kernel<<<N_ROWS / 4, 256, 0, stream>>>(cand, cnts, chunkmin,
                                                      z, cb, zz, cnorm,
                                                      out_zq, out_idx, rowsum);
        loss_kernel<<<1, 256, 0, stream>>>(rowsum, out_loss);
    } else {
        // fallback: verified round-2 fp32 path (~1 MB ws)
        float* pval = rowsum + N_ROWS;
        int*   pidx = (int*)(pval + (size_t)N_ROWS * NCHUNK);
        rownorm_np_kernel<<<(N_ROWS * 4) / 256, 256, 0, stream>>>(z, N_ROWS, zz);
        rownorm_np_kernel<<<(K_CODES * 4) / 256, 256, 0, stream>>>(cb, K_CODES, cnorm);
        dim3 g2(NCHUNK, N_ROWS / BM);
        vq_argmin_kernel<<<g2, 256, 0, stream>>>(z, cb, zz, cnorm, pval, pidx);
        finalize_kernel<<<N_ROWS / 4, 256, 0, stream>>>(z, cb, pval, pidx,
                                                        out_zq, out_idx, rowsum);
        loss_kernel<<<1, 256, 0, stream>>>(rowsum, out_loss);
    }
}

// Round 12
// 247.980 us; speedup vs baseline: 1.1789x; 1.0296x over previous
//
#include <hip/hip_runtime.h>
#include <math.h>

#define N_ROWS 16384
#define K_CODES 4096
#define D_DIM 512
#define NCHUNK 8
#define KCHUNK (K_CODES / NCHUNK)
#define MARGIN 2.5e-3f
#define CCAP 32   // per-row per-chunk candidate cap (expected ~1-4 used)

typedef unsigned int uint32;
typedef unsigned short u16t;
typedef __attribute__((ext_vector_type(8))) short short8;
typedef __attribute__((ext_vector_type(4))) float f32x4;

__device__ __forceinline__ float fmul_(float a, float b) { return __fmul_rn(a, b); }
__device__ __forceinline__ float fadd_(float a, float b) { return __fadd_rn(a, b); }

// ---------------------------------------------------------------- cvt bf16
__device__ __forceinline__ u16t f2bf(float x) {
    uint32 u = __float_as_uint(x);
    return (u16t)((u + 0x7fffu + ((u >> 16) & 1u)) >> 16);   // RNE
}
// order-preserving float<->uint key for LDS atomicMin on floats (incl. negatives)
__device__ __forceinline__ uint32 fkey(float f) {
    uint32 u = __float_as_uint(f);
    return (u & 0x80000000u) ? ~u : (u | 0x80000000u);
}
__device__ __forceinline__ float fdec(uint32 k) {
    uint32 u = (k & 0x80000000u) ? (k ^ 0x80000000u) : ~k;
    return __uint_as_float(u);
}
// min across each contiguous 16-lane group, pure-VALU DPP (no ds_swizzle).
__device__ __forceinline__ float dpp_min16(float x) {
    int y;
    y = __builtin_amdgcn_update_dpp(0, __float_as_int(x), 0xB1, 0xf, 0xf, true);
    x = fminf(x, __int_as_float(y));
    y = __builtin_amdgcn_update_dpp(0, __float_as_int(x), 0x4E, 0xf, 0xf, true);
    x = fminf(x, __int_as_float(y));
    y = __builtin_amdgcn_update_dpp(0, __float_as_int(x), 0x141, 0xf, 0xf, true);
    x = fminf(x, __int_as_float(y));
    y = __builtin_amdgcn_update_dpp(0, __float_as_int(x), 0x140, 0xf, 0xf, true);
    x = fminf(x, __int_as_float(y));
    return x;
}

// ---------------------------------------------------------------- prep
// FUSED cvt_bf16 + rownorm (verified R7): reads each input once, row-norm
// arithmetic byte-identical to the verified rownorm_np_kernel.
__global__ void prep_kernel(const float* __restrict__ z,
                            const float* __restrict__ cb,
                            u16t* __restrict__ z_bf, u16t* __restrict__ cb_bf,
                            float* __restrict__ zz, float* __restrict__ cnorm) {
    int gid = blockIdx.x * blockDim.x + threadIdx.x;
    int row = gid >> 2;
    int blk = gid & 3;
    const float* src;
    u16t* dst;
    float* outn;
    if (row < N_ROWS) {
        src = z + (size_t)row * D_DIM;
        dst = z_bf + (size_t)row * D_DIM;
        outn = zz + row;
    } else {
        int r = row - N_ROWS;
        if (r >= K_CODES) return;
        src = cb + (size_t)r * D_DIM;
        dst = cb_bf + (size_t)r * D_DIM;
        outn = cnorm + r;
    }
    const float4* p = (const float4*)(src + blk * 128);
    u16t* d = dst + blk * 128;
    float4 v0 = p[0], v1 = p[1];
    {
        short8 o;
        o[0] = (short)f2bf(v0.x); o[1] = (short)f2bf(v0.y);
        o[2] = (short)f2bf(v0.z); o[3] = (short)f2bf(v0.w);
        o[4] = (short)f2bf(v1.x); o[5] = (short)f2bf(v1.y);
        o[6] = (short)f2bf(v1.z); o[7] = (short)f2bf(v1.w);
        *(short8*)d = o;
    }
    float r0 = fmul_(v0.x, v0.x), r1 = fmul_(v0.y, v0.y);
    float r2 = fmul_(v0.z, v0.z), r3 = fmul_(v0.w, v0.w);
    float r4 = fmul_(v1.x, v1.x), r5 = fmul_(v1.y, v1.y);
    float r6 = fmul_(v1.z, v1.z), r7 = fmul_(v1.w, v1.w);
#pragma unroll
    for (int i = 1; i < 16; i++) {
        float4 w0 = p[2 * i], w1 = p[2 * i + 1];
        {
            short8 o;
            o[0] = (short)f2bf(w0.x); o[1] = (short)f2bf(w0.y);
            o[2] = (short)f2bf(w0.z); o[3] = (short)f2bf(w0.w);
            o[4] = (short)f2bf(w1.x); o[5] = (short)f2bf(w1.y);
            o[6] = (short)f2bf(w1.z); o[7] = (short)f2bf(w1.w);
            *(short8*)(d + i * 8) = o;
        }
        r0 = fadd_(r0, fmul_(w0.x, w0.x));
        r1 = fadd_(r1, fmul_(w0.y, w0.y));
        r2 = fadd_(r2, fmul_(w0.z, w0.z));
        r3 = fadd_(r3, fmul_(w0.w, w0.w));
        r4 = fadd_(r4, fmul_(w1.x, w1.x));
        r5 = fadd_(r5, fmul_(w1.y, w1.y));
        r6 = fadd_(r6, fmul_(w1.z, w1.z));
        r7 = fadd_(r7, fmul_(w1.w, w1.w));
    }
    float s = fadd_(fadd_(fadd_(r0, r1), fadd_(r2, r3)),
                    fadd_(fadd_(r4, r5), fadd_(r6, r7)));
    float u = __shfl_down(s, 1, 64);
    float t = fadd_(s, u);
    float w = __shfl_down(t, 2, 64);
    float tot = fadd_(t, w);
    if (blk == 0) *outn = tot;
}

// ---------------------------------------------------------------- rownorm
// (kept for the fallback path; verified R2/R3)
__global__ void rownorm_np_kernel(const float* __restrict__ src, int nrows,
                                  float* __restrict__ out) {
    int gid = blockIdx.x * blockDim.x + threadIdx.x;
    int row = gid >> 2;
    int blk = gid & 3;
    if (row >= nrows) return;
    const float4* p = (const float4*)(src + (size_t)row * D_DIM + blk * 128);
    float4 v0 = p[0], v1 = p[1];
    float r0 = fmul_(v0.x, v0.x), r1 = fmul_(v0.y, v0.y);
    float r2 = fmul_(v0.z, v0.z), r3 = fmul_(v0.w, v0.w);
    float r4 = fmul_(v1.x, v1.x), r5 = fmul_(v1.y, v1.y);
    float r6 = fmul_(v1.z, v1.z), r7 = fmul_(v1.w, v1.w);
#pragma unroll
    for (int i = 1; i < 16; i++) {
        float4 w0 = p[2 * i], w1 = p[2 * i + 1];
        r0 = fadd_(r0, fmul_(w0.x, w0.x));
        r1 = fadd_(r1, fmul_(w0.y, w0.y));
        r2 = fadd_(r2, fmul_(w0.z, w0.z));
        r3 = fadd_(r3, fmul_(w0.w, w0.w));
        r4 = fadd_(r4, fmul_(w1.x, w1.x));
        r5 = fadd_(r5, fmul_(w1.y, w1.y));
        r6 = fadd_(r6, fmul_(w1.z, w1.z));
        r7 = fadd_(r7, fmul_(w1.w, w1.w));
    }
    float s = fadd_(fadd_(fadd_(r0, r1), fadd_(r2, r3)),
                    fadd_(fadd_(r4, r5), fadd_(r6, r7)));
    float u = __shfl_down(s, 1, 64);
    float t = fadd_(s, u);
    float w = __shfl_down(t, 2, 64);
    float tot = fadd_(t, w);
    if (blk == 0) out[row] = tot;
}

// ---------------------------------------------------------------- phase 1
// bf16 MFMA GEMM, fused epilogue. R12: T2 + T4 COMBINED.
// R10 (T4 alone): null -- LDS 8-way conflict dominated the round.
// R11 (T2 alone): +6% -- conflicts fixed, stage-drain now dominates.
// Catalog regime gate (m252): each technique is invisible without the
// other. This round: R11's swizzle verbatim + R10's counted-vmcnt 2-deep
// pipeline verbatim. vmcnt-store audit: pass-2 cand stores precede the
// prologue loads in program order, so waiting to vmcnt<=4 always retires
// them along with slab dt's loads (R10 was bit-exact for this reason).
//   T2: source col pre-swizzled qg = ((t&3)-((t>>3)&3))&3, linear LDS dest;
//       read slot sl16 = ((quad+(l15>>1))&3)*16 -- same involution.
//   T4: stage slabs 0,1; per dt: vmcnt(4|0) -> raw s_barrier -> compute
//       buf[dt&1] -> raw s_barrier -> stage slab dt+2. Never vmcnt(0)
//       mid-loop.
#define STAGE4(gaP, gbP, bufA, bufB)                                        \
    do {                                                                    \
        __builtin_amdgcn_global_load_lds(                                   \
            (const __attribute__((address_space(1))) void*)(gaP),           \
            (__attribute__((address_space(3))) void*)((char*)(bufA) + w * 1024), 16, 0, 0); \
        __builtin_amdgcn_global_load_lds(                                   \
            (const __attribute__((address_space(1))) void*)((gaP) + 32),    \
            (__attribute__((address_space(3))) void*)((char*)(bufA) + 8192 + w * 1024), 16, 0, 0); \
        __builtin_amdgcn_global_load_lds(                                   \
            (const __attribute__((address_space(1))) void*)(gbP),           \
            (__attribute__((address_space(3))) void*)((char*)(bufB) + w * 1024), 16, 0, 0); \
        __builtin_amdgcn_global_load_lds(                                   \
            (const __attribute__((address_space(1))) void*)((gbP) + 32),    \
            (__attribute__((address_space(3))) void*)((char*)(bufB) + 8192 + w * 1024), 16, 0, 0); \
    } while (0)

__global__ __launch_bounds__(512, 4) void score_gemm_kernel(
    const u16t* __restrict__ zb, const u16t* __restrict__ cbb,
    const float* __restrict__ cnorm,
    float* __restrict__ chunkmin,      // [N_ROWS][NCHUNK]
    uint32* __restrict__ cnts,         // [N_ROWS][NCHUNK]
    uint2* __restrict__ cand) {        // [N_ROWS][NCHUNK][CCAP] {sbits,k}
    __shared__ alignas(16) u16t Ab[2][128 * 64];   // 2 x 16 KB
    __shared__ alignas(16) u16t Bb[2][128 * 64];
    __shared__ uint32 rowminU[128];    // running chunk min (monotone key)
    __shared__ int ccnt[128];          // per-row candidate count (this chunk)

    const int t = threadIdx.x;
    const int panel = blockIdx.x;      // row-panel index (XCD = panel % 8)
    const int chunk = blockIdx.y;      // codebook chunk index
    const int row0 = panel * 128, k0 = chunk * KCHUNK;
    const int w = t >> 6, lane = t & 63;
    const int wx = w & 1, wy = w >> 1;           // wx: col half, wy: row quarter
    const int l15 = lane & 15, quad = lane >> 4;
    // T2 swizzle terms (see header comment)
    const int qg = ((t & 3) - ((t >> 3) & 3)) & 3;      // staging source slot
    const int sl16 = (((quad + (l15 >> 1)) & 3) << 4);  // read slot byte offset

    if (t < 128) { rowminU[t] = 0xFFFFFFFFu; ccnt[t] = 0; }
    // (ordered before first epilogue use by the dt=0 barrier of kt=0)

    for (int kt = 0; kt < 4; kt++) {
        f32x4 acc[2][4];
#pragma unroll
        for (int i = 0; i < 2; i++)
#pragma unroll
            for (int j = 0; j < 4; j++) acc[i][j] = (f32x4){0.f, 0.f, 0.f, 0.f};

        // per-thread global cursors (wave w stages rows w*16..w*16+15);
        // column = qg*8 (pre-swizzled source; linear LDS dest)
        const u16t* ga = zb + (size_t)(row0 + (t >> 2)) * D_DIM + qg * 8;
        const u16t* gb = cbb + (size_t)(k0 + kt * 128 + (t >> 2)) * D_DIM + qg * 8;

        // ---- prologue: slabs 0,1 -> buffers 0,1 (8 loads in flight) ----
        STAGE4(ga, gb, Ab[0], Bb[0]);  ga += 64; gb += 64;
        STAGE4(ga, gb, Ab[1], Bb[1]);  ga += 64; gb += 64;

        for (int dt = 0; dt < 8; dt++) {          // 8 x 64-dim slabs
            const int cur = dt & 1;
            // wait for slab dt only; slab dt+1's 4 loads remain in flight
            if (dt < 7) asm volatile("s_waitcnt vmcnt(4)" ::: "memory");
            else        asm volatile("s_waitcnt vmcnt(0)" ::: "memory");
            __builtin_amdgcn_s_barrier();         // slab dt visible to all
            __builtin_amdgcn_sched_barrier(0);
#pragma unroll
            for (int sub = 0; sub < 2; sub++) {
                short8 a[2];
#pragma unroll
                for (int i = 0; i < 2; i++)
                    a[i] = *(const short8*)((char*)Ab[cur] + sub * 8192 +
                                            (wy * 32 + i * 16 + l15) * 64 + sl16);
#pragma unroll
                for (int j = 0; j < 4; j++) {
                    short8 b = *(const short8*)((char*)Bb[cur] + sub * 8192 +
                                                (wx * 64 + j * 16 + l15) * 64 + sl16);
#pragma unroll
                    for (int i = 0; i < 2; i++)
                        acc[i][j] = __builtin_amdgcn_mfma_f32_16x16x32_bf16(a[i], b, acc[i][j], 0, 0, 0);
                }
            }
            __builtin_amdgcn_s_barrier();         // all waves done reading buf[cur]
            __builtin_amdgcn_sched_barrier(0);
            if (dt < 6) {                         // stage slab dt+2 into buf[cur]
                STAGE4(ga, gb, Ab[cur], Bb[cur]);  ga += 64; gb += 64;
            }
        }

        // ---- fused epilogue ----
        float cnj[4];
#pragma unroll
        for (int j = 0; j < 4; j++)
            cnj[j] = cnorm[k0 + kt * 128 + wx * 64 + j * 16 + l15];

        // pass 1: per-row running min (per-thread j-min + DPP row-min)
#pragma unroll
        for (int i = 0; i < 2; i++) {
#pragma unroll
            for (int r = 0; r < 4; r++) {
                float m = fmaf(-2.f, acc[i][0][r], cnj[0]);
                m = fminf(m, fmaf(-2.f, acc[i][1][r], cnj[1]));
                m = fminf(m, fmaf(-2.f, acc[i][2][r], cnj[2]));
                m = fminf(m, fmaf(-2.f, acc[i][3][r], cnj[3]));
                m = dpp_min16(m);                 // min over the 16 l15 lanes
                if (l15 == 0)
                    atomicMin(&rowminU[wy * 32 + i * 16 + quad * 4 + r], fkey(m));
            }
        }
        __syncthreads();
        // pass 2: append candidates vs running-min threshold (superset-safe;
        // refine re-filters with the exact global min)
#pragma unroll
        for (int i = 0; i < 2; i++) {
#pragma unroll
            for (int r = 0; r < 4; r++) {
                const int rl = wy * 32 + i * 16 + quad * 4 + r;
                const float thr = fdec(rowminU[rl]) + MARGIN;
#pragma unroll
                for (int j = 0; j < 4; j++) {
                    float s = fmaf(-2.f, acc[i][j][r], cnj[j]);
                    if (s <= thr) {
                        int pos = atomicAdd(&ccnt[rl], 1);
                        if (pos < CCAP) {
                            uint2 e;
                            e.x = __float_as_uint(s);
                            e.y = (uint32)(k0 + kt * 128 + wx * 64 + j * 16 + l15);
                            cand[((size_t)(row0 + rl) * NCHUNK + chunk) * CCAP + pos] = e;
                        }
                    }
                }
            }
        }
        // next kt's dt=0 barrier orders pass2 reads of rowminU before the
        // next kt's pass-1 atomicMin updates
    }
    __syncthreads();
    if (t < 128) {
        chunkmin[(size_t)(row0 + t) * NCHUNK + chunk] = fdec(rowminU[t]);
        int c = ccnt[t];
        cnts[(size_t)(row0 + t) * NCHUNK + chunk] = (uint32)(c < CCAP ? c : CCAP);
    }
}

// ---------------------------------------------------------------- phase 2
// ONE WAVE PER ROW, zero barriers, zero LDS (verified R6 structure).
__global__ __launch_bounds__(256) void refine_kernel(
    const uint2* __restrict__ cand, const uint32* __restrict__ cnts,
    const float* __restrict__ chunkmin,
    const float* __restrict__ z, const float* __restrict__ cb,
    const float* __restrict__ zz, const float* __restrict__ cnorm,
    float* __restrict__ out_zq, float* __restrict__ out_idx,
    float* __restrict__ rowsum) {
    const int t = threadIdx.x;
    const int wid = t >> 6, lane = t & 63;
    const int row = blockIdx.x * 4 + wid;

    // global coarse min over the 8 chunk minima (fminf is order-independent)
    float cm = chunkmin[(size_t)row * NCHUNK + (lane & 7)];
    cm = fminf(cm, __shfl_xor(cm, 1, 64));
    cm = fminf(cm, __shfl_xor(cm, 2, 64));
    cm = fminf(cm, __shfl_xor(cm, 4, 64));
    const float thr = cm + MARGIN;

    // z row into regs (verified layout: lane covers elements lane*8..lane*8+7)
    const float* zr = z + (size_t)row * D_DIM;
    float4 z0 = *(const float4*)(zr + lane * 8);
    float4 z1 = *(const float4*)(zr + lane * 8 + 4);
    const float zzr = zz[row];

    float bv = 3.4e38f;
    int bi = 0x7fffffff;
#pragma unroll
    for (int it = 0; it < (NCHUNK * CCAP) / 64; ++it) {
        int idx = it * 64 + lane;
        int c = idx >> 5, s2 = idx & (CCAP - 1);
        uint32 n = cnts[(size_t)row * NCHUNK + c];
        int kk = -1;
        if ((uint32)s2 < n) {
            uint2 e = cand[((size_t)row * NCHUNK + c) * CCAP + s2];
            if (__uint_as_float(e.x) <= thr) kk = (int)e.y;
        }
        unsigned long long mask = __ballot(kk >= 0);
        while (mask) {
            int src = __ffsll((unsigned long long)mask) - 1;
            mask &= (mask - 1);
            int k = __shfl(kk, src, 64);
            // exact np-fp32 dist (verified R3 instruction sequence)
            const float* cr = cb + (size_t)k * D_DIM;
            float4 c0 = *(const float4*)(cr + lane * 8);
            float4 c1 = *(const float4*)(cr + lane * 8 + 4);
            float d = fmul_(z0.x, c0.x);
            d = fmaf(z0.y, c0.y, d); d = fmaf(z0.z, c0.z, d); d = fmaf(z0.w, c0.w, d);
            d = fmaf(z1.x, c1.x, d); d = fmaf(z1.y, c1.y, d);
            d = fmaf(z1.z, c1.z, d); d = fmaf(z1.w, c1.w, d);
#pragma unroll
            for (int off = 1; off < 64; off <<= 1)
                d = fadd_(d, __shfl_xor(d, off, 64));
            float dist = fmaf(-2.f, d, fadd_(zzr, cnorm[k]));
            // (value, index) tie-break; wave-uniform after the full reduce
            if (dist < bv || (dist == bv && k < bi)) { bv = dist; bi = k; }
        }
    }
    // defensive clamp: never let a pathological empty list read OOB
    if (bi == 0x7fffffff) bi = 0;
    if (lane == 0) out_idx[row] = (float)bi;

    // STE + rowsum (verified bit-exact tree via lane-leaf layout)
    const float* cq = cb + (size_t)bi * D_DIM;
    float v[4];
#pragma unroll
    for (int q = 0; q < 4; q++) {
        const int off = q * 128 + lane * 2;
        float2 zv2 = *(const float2*)(zr + off);
        float2 cv2 = *(const float2*)(cq + off);
        float2 o;
        o.x = fadd_(zv2.x, __fsub_rn(cv2.x, zv2.x));
        o.y = fadd_(zv2.y, __fsub_rn(cv2.y, zv2.y));
        *(float2*)(out_zq + (size_t)row * D_DIM + off) = o;
        float dx = zv2.x - cv2.x, dy = zv2.y - cv2.y;
        v[q] = dx * dx + dy * dy;
    }
    float s = fadd_(fadd_(v[0], v[2]), fadd_(v[1], v[3]));
    s = fadd_(s, __shfl_down(s, 32, 64));
    s = fadd_(s, __shfl_down(s, 16, 64));
    s = fadd_(s, __shfl_down(s, 8, 64));
    s = fadd_(s, __shfl_down(s, 4, 64));
    s = fadd_(s, __shfl_down(s, 2, 64));
    s = fadd_(s, __shfl_down(s, 1, 64));
    if (lane == 0) rowsum[row] = s;
}

// ---------------------------------------------------------------- loss
__global__ void loss_kernel(const float* __restrict__ rowsum,
                            float* __restrict__ out_loss) {
    __shared__ float sm[256];
    float s = 0.f;
    for (int i = threadIdx.x; i < N_ROWS; i += 256) s += rowsum[i];
    sm[threadIdx.x] = s;
    __syncthreads();
    for (int st = 128; st; st >>= 1) {
        if (threadIdx.x < st) sm[threadIdx.x] += sm[threadIdx.x + st];
        __syncthreads();
    }
    if (threadIdx.x == 0)
        *out_loss = 1.25f * sm[0] / (float)(N_ROWS * D_DIM);
}

// ================================================================ fallback
// (verified round-2 fp32 path, used only if ws_size too small)
#define BM 128
#define BN 128
#define BK 16
#define TM 8
#define TN 8

__global__ __launch_bounds__(256, 4) void vq_argmin_kernel(
    const float* __restrict__ z, const float* __restrict__ cb,
    const float* __restrict__ zz, const float* __restrict__ cnorm,
    float* __restrict__ pval, int* __restrict__ pidx) {
    __shared__ float As[BK][BM + 4];
    __shared__ float Bs[BK][BN + 4];
    __shared__ float rv[BM][17];
    __shared__ int   ri[BM][17];

    const int bx = blockIdx.x;
    const int by = blockIdx.y;
    const int row0 = by * BM;
    const int k0 = bx * KCHUNK;
    const int t = threadIdx.x;
    const int tx = t & 15;
    const int ty = t >> 4;

    float minv[TM];
    int   mini[TM];
#pragma unroll
    for (int i = 0; i < TM; i++) { minv[i] = 3.4e38f; mini[i] = 0; }
    float zrow[TM];
#pragma unroll
    for (int i = 0; i < TM; i++) zrow[i] = zz[row0 + ty * TM + i];
    const int sr = t >> 1;
    const int sdq = (t & 1) * 8;

    for (int kt = 0; kt < KCHUNK / BN; kt++) {
        const int col0 = k0 + kt * BN;
        float acc[TM][TN];
#pragma unroll
        for (int i = 0; i < TM; i++)
#pragma unroll
            for (int j = 0; j < TN; j++) acc[i][j] = 0.f;
        for (int dt = 0; dt < D_DIM; dt += BK) {
            {
                const float* src = z + (size_t)(row0 + sr) * D_DIM + dt + sdq;
                float4 v0 = *(const float4*)(src);
                float4 v1 = *(const float4*)(src + 4);
                As[sdq + 0][sr] = v0.x; As[sdq + 1][sr] = v0.y;
                As[sdq + 2][sr] = v0.z; As[sdq + 3][sr] = v0.w;
                As[sdq + 4][sr] = v1.x; As[sdq + 5][sr] = v1.y;
                As[sdq + 6][sr] = v1.z; As[sdq + 7][sr] = v1.w;
                const float* srcb = cb + (size_t)(col0 + sr) * D_DIM + dt + sdq;
                float4 w0 = *(const float4*)(srcb);
                float4 w1 = *(const float4*)(srcb + 4);
                Bs[sdq + 0][sr] = w0.x; Bs[sdq + 1][sr] = w0.y;
                Bs[sdq + 2][sr] = w0.z; Bs[sdq + 3][sr] = w0.w;
                Bs[sdq + 4][sr] = w1.x; Bs[sdq + 5][sr] = w1.y;
                Bs[sdq + 6][sr] = w1.z; Bs[sdq + 7][sr] = w1.w;
            }
            __syncthreads();
#pragma unroll
            for (int d = 0; d < BK; d++) {
                float a[TM], b[TN];
#pragma unroll
                for (int i = 0; i < TM; i++) a[i] = As[d][ty * TM + i];
#pragma unroll
                for (int j = 0; j < TN; j++) b[j] = Bs[d][tx * TN + j];
#pragma unroll
                for (int i = 0; i < TM; i++)
#pragma unroll
                    for (int j = 0; j < TN; j++)
                        acc[i][j] = fmaf(a[i], b[j], acc[i][j]);
            }
            __syncthreads();
        }
#pragma unroll
        for (int j = 0; j < TN; j++) {
            const int col = col0 + tx * TN + j;
            const float cn = cnorm[col];
#pragma unroll
            for (int i = 0; i < TM; i++) {
                float s1 = fadd_(zrow[i], cn);
                float s = fmaf(-2.f, acc[i][j], s1);
                if (s < minv[i]) { minv[i] = s; mini[i] = col; }
            }
        }
    }
#pragma unroll
    for (int i = 0; i < TM; i++) {
        rv[ty * TM + i][tx] = minv[i];
        ri[ty * TM + i][tx] = mini[i];
    }
    __syncthreads();
    if (t < BM) {
        float bv = rv[t][0];
        int   bi = ri[t][0];
#pragma unroll
        for (int x = 1; x < 16; x++) {
            float v = rv[t][x]; int ii = ri[t][x];
            if (v < bv || (v == bv && ii < bi)) { bv = v; bi = ii; }
        }
        pval[(size_t)(row0 + t) * NCHUNK + bx] = bv;
        pidx[(size_t)(row0 + t) * NCHUNK + bx] = bi;
    }
}

__global__ void finalize_kernel(const float* __restrict__ z,
                                const float* __restrict__ cb,
                                const float* __restrict__ pval,
                                const int* __restrict__ pidx,
                                float* __restrict__ out_zq,
                                float* __restrict__ out_idx,
                                float* __restrict__ rowsum) {
    int row = (blockIdx.x * blockDim.x + threadIdx.x) >> 6;
    int lane = threadIdx.x & 63;
    if (row >= N_ROWS) return;
    float bv = pval[(size_t)row * NCHUNK];
    int   bi = pidx[(size_t)row * NCHUNK];
#pragma unroll
    for (int c = 1; c < NCHUNK; c++) {
        float v = pval[(size_t)row * NCHUNK + c];
        int  ii = pidx[(size_t)row * NCHUNK + c];
        if (v < bv || (v == bv && ii < bi)) { bv = v; bi = ii; }
    }
    const float4* zr = (const float4*)(z + (size_t)row * D_DIM);
    const float4* cr = (const float4*)(cb + (size_t)bi * D_DIM);
    float4* orow = (float4*)(out_zq + (size_t)row * D_DIM);
    float s = 0.f;
#pragma unroll
    for (int i = 0; i < 2; i++) {
        float4 zv = zr[i * 64 + lane];
        float4 cv = cr[i * 64 + lane];
        float4 o;
        o.x = fadd_(zv.x, __fsub_rn(cv.x, zv.x));
        o.y = fadd_(zv.y, __fsub_rn(cv.y, zv.y));
        o.z = fadd_(zv.z, __fsub_rn(cv.z, zv.z));
        o.w = fadd_(zv.w, __fsub_rn(cv.w, zv.w));
        orow[i * 64 + lane] = o;
        float dx = zv.x - cv.x, dy = zv.y - cv.y;
        float dz = zv.z - cv.z, dw = zv.w - cv.w;
        s += dx * dx + dy * dy + dz * dz + dw * dw;
    }
#pragma unroll
    for (int off = 32; off; off >>= 1) s += __shfl_down(s, off, 64);
    if (lane == 0) {
        rowsum[row] = s;
        out_idx[row] = (float)bi;
    }
}

// ---------------------------------------------------------------- launch
extern "C" void kernel_launch(void* const* d_in, const int* in_sizes, int n_in,
                              void* d_out, int out_size, void* d_ws, size_t ws_size,
                              hipStream_t stream) {
    const float* z  = (const float*)d_in[0];
    const float* cb = (const float*)d_in[1];
    float* out      = (float*)d_out;
    float* out_zq   = out;
    float* out_idx  = out + (size_t)N_ROWS * D_DIM;
    float* out_loss = out_idx + N_ROWS;

    float* zz     = (float*)d_ws;                          // 16384 f32
    float* cnorm  = zz + N_ROWS;                           // 4096 f32
    float* rowsum = cnorm + K_CODES;                       // 16384 f32
    u16t*  z_bf   = (u16t*)(rowsum + N_ROWS);              // 16384*512 u16
    u16t*  cb_bf  = z_bf + (size_t)N_ROWS * D_DIM;         // 4096*512 u16
    float* chunkmin = (float*)(cb_bf + (size_t)K_CODES * D_DIM);   // 16384*8 f32
    uint32* cnts  = (uint32*)(chunkmin + (size_t)N_ROWS * NCHUNK); // 16384*8 u32
    uint2* cand   = (uint2*)(cnts + (size_t)N_ROWS * NCHUNK);      // 16384*8*32 uint2
    const size_t WS_NEEDED = (size_t)(N_ROWS + K_CODES + N_ROWS) * 4
                           + (size_t)N_ROWS * D_DIM * 2
                           + (size_t)K_CODES * D_DIM * 2
                           + (size_t)N_ROWS * NCHUNK * 4 * 2
                           + (size_t)N_ROWS * NCHUNK * CCAP * 8;

    if (ws_size >= WS_NEEDED) {
        prep_kernel<<<((N_ROWS + K_CODES) * 4) / 256, 256, 0, stream>>>(
            z, cb, z_bf, cb_bf, zz, cnorm);

        dim3 g1(N_ROWS / 128, NCHUNK);   // x = row-panel (XCD key), y = chunk
        score_gemm_kernel<<<g1, 512, 0, stream>>>(z_bf, cb_bf, cnorm,
                                                  chunkmin, cnts, cand);
        refine_kernel<<<N_ROWS / 4, 256, 0, stream>>>(cand, cnts, chunkmin,
                                                      z, cb, zz, cnorm,
                                                      out_zq, out_idx, rowsum);
        loss_kernel<<<1, 256, 0, stream>>>(rowsum, out_loss);
    } else {
        // fallback: verified round-2 fp32 path (~1 MB ws)
        float* pval = rowsum + N_ROWS;
        int*   pidx = (int*)(pval + (size_t)N_ROWS * NCHUNK);
        rownorm_np_kernel<<<(N_ROWS * 4) / 256, 256, 0, stream>>>(z, N_ROWS, zz);
        rownorm_np_kernel<<<(K_CODES * 4) / 256, 256, 0, stream>>>(cb, K_CODES, cnorm);
        dim3 g2(NCHUNK, N_ROWS / BM);
        vq_argmin_kernel<<<g2, 256, 0, stream>>>(z, cb, zz, cnorm, pval, pidx);
        finalize_kernel<<<N_ROWS / 4, 256, 0, stream>>>(z, cb, pval, pidx,
                                                        out_zq, out_idx, rowsum);
        loss_kernel<<<1, 256, 0, stream>>>(rowsum, out_loss);
    }
}